// Round 9
// baseline (317.246 us; speedup 1.0000x reference)
//
#include <hip/hip_runtime.h>
#include <hip/hip_bf16.h>
#include <math.h>

// dims
#define B_ 32
#define L_ 64
#define D_ 256
#define H_ 8
#define T_ 65
#define NT_ (B_*T_)   // 2080
#define DFF_ 2048
#define S_ 16
#define I_ 16
#define DSEM_ 128

typedef __attribute__((ext_vector_type(8))) short bf16x8;
typedef __attribute__((ext_vector_type(4))) float f32x4;

typedef __attribute__((address_space(1))) const void gbl_void;
typedef __attribute__((address_space(3))) void lds_void;
#define GLOAD16(g, l) __builtin_amdgcn_global_load_lds((gbl_void*)(g), (lds_void*)(l), 16, 0, 0)

__device__ inline unsigned short f2bu(float f) {
  union { float f; unsigned u; } a; a.f = f;
  unsigned r = a.u + 0x7FFF + ((a.u >> 16) & 1);
  return (unsigned short)(r >> 16);
}
__device__ inline float b2f(unsigned short u) {
  union { unsigned u; float f; } a; a.u = ((unsigned)u) << 16;
  return a.f;
}

__device__ inline float wave_reduce_sum(float v) {
#pragma unroll
  for (int m = 32; m >= 1; m >>= 1) v += __shfl_xor(v, m, 64);
  return v;
}

__device__ inline float block_reduce_sum_256(float v, float* sred) {
  v = wave_reduce_sum(v);
  int tid = threadIdx.x;
  if ((tid & 63) == 0) sred[tid >> 6] = v;
  __syncthreads();
  float r = sred[0] + sred[1] + sred[2] + sred[3];
  __syncthreads();
  return r;
}

// ---------------- fused converters (concat | W_feat transpose | 4x weight conv) ----------------
__global__ __launch_bounds__(256) void conv_fused_kernel(
    const float* __restrict__ dense, const float* __restrict__ sparse, unsigned short* __restrict__ cat,
    const float* __restrict__ wfeat, unsigned short* __restrict__ wfeatT,
    const float* __restrict__ ipw, const float* __restrict__ ow,
    const float* __restrict__ f1w, const float* __restrict__ f2w,
    unsigned short* __restrict__ ipwB, unsigned short* __restrict__ owB,
    unsigned short* __restrict__ f1wB, unsigned short* __restrict__ f2wB) {
  __shared__ float tb[64][65];
  int bid = blockIdx.x, tid = threadIdx.x;
  if (bid < 2048) {
    int idx = bid * 256 + tid;
    int r = idx >> 8, c = idx & 255;
    float v = (c < 128) ? dense[r * 128 + c] : sparse[r * 128 + (c - 128)];
    cat[idx] = f2bu(v);
  } else if (bid < 2064) {
    int blk = bid - 2048;
    int k0 = (blk & 3) * 64, n0 = (blk >> 2) * 64;
    int wid = tid >> 6, lane = tid & 63;
#pragma unroll
    for (int p = 0; p < 16; ++p)
      tb[p * 4 + wid][lane] = wfeat[(size_t)(k0 + p * 4 + wid) * 256 + n0 + lane];
    __syncthreads();
#pragma unroll
    for (int p = 0; p < 16; ++p)
      wfeatT[(size_t)(n0 + p * 4 + wid) * 256 + k0 + lane] = f2bu(tb[lane][p * 4 + wid]);
  } else {
    int i = (bid - 2064) * 256 + tid;  // over 655360 float4s
    const float* src; unsigned short* dst; int off;
    if (i < 98304)       { src = ipw; dst = ipwB; off = i; }
    else if (i < 131072) { src = ow;  dst = owB;  off = i - 98304; }
    else if (i < 393216) { src = f1w; dst = f1wB; off = i - 131072; }
    else                 { src = f2w; dst = f2wB; off = i - 393216; }
    float4 v = ((const float4*)src)[off];
    short4 o;
    o.x = (short)f2bu(v.x); o.y = (short)f2bu(v.y);
    o.z = (short)f2bu(v.z); o.w = (short)f2bu(v.w);
    ((short4*)dst)[off] = o;
  }
}

// ---------------- bf16 MFMA GEMM (NT): C[M,N] = act(A[M,K] @ W[N,K]^T + bias) ----------------
template <int ACT, int OUT_BF16, int NFRAG>
__global__ __launch_bounds__(256) void gemm_bf2_kernel(const unsigned short* __restrict__ A,
                                                       const unsigned short* __restrict__ W,
                                                       const float* __restrict__ bias,
                                                       float* __restrict__ Cf, unsigned short* __restrict__ Cb,
                                                       int M, int N, int K) {
  __shared__ __align__(16) unsigned short As[2][32 * 64];
  __shared__ __align__(16) unsigned short Bs[2][NFRAG * 64 * 64];
  int tid = threadIdx.x, wid = tid >> 6, lane = tid & 63;
  int row0 = blockIdx.y * 32, col0 = blockIdx.x * (64 * NFRAG);
  int lr = lane >> 3;
  int sc = ((lane & 7) ^ (lr & 7)) << 3;
  const unsigned short* Asrc = A + (size_t)(row0 + wid * 8 + lr) * K + sc;
  const unsigned short* Bsrc[2 * NFRAG];
#pragma unroll
  for (int p = 0; p < 2 * NFRAG; ++p)
    Bsrc[p] = W + (size_t)(col0 + wid * 16 * NFRAG + p * 8 + lr) * K + sc;
  unsigned short* AsW = &As[0][0] + wid * (8 * 64);
  unsigned short* BsW = &Bs[0][0] + wid * (16 * NFRAG * 64);

  f32x4 acc[2][NFRAG];
#pragma unroll
  for (int i = 0; i < 2; ++i)
#pragma unroll
    for (int j = 0; j < NFRAG; ++j) acc[i][j] = (f32x4){0.f, 0.f, 0.f, 0.f};

  GLOAD16(Asrc, AsW);
#pragma unroll
  for (int p = 0; p < 2 * NFRAG; ++p) GLOAD16(Bsrc[p], BsW + p * (8 * 64));

  int nk = K >> 6, cur = 0;
  int kg = lane >> 4, l15 = lane & 15;
  for (int kt = 0; kt < nk; ++kt) {
    __syncthreads();
    if (kt + 1 < nk) {
      int k0 = (kt + 1) << 6;
      GLOAD16(Asrc + k0, AsW + (cur ^ 1) * (32 * 64));
#pragma unroll
      for (int p = 0; p < 2 * NFRAG; ++p)
        GLOAD16(Bsrc[p] + k0, BsW + (cur ^ 1) * (NFRAG * 64 * 64) + p * (8 * 64));
    }
    const unsigned short* Ab = &As[cur][0];
    const unsigned short* Bb = &Bs[cur][0];
#pragma unroll
    for (int kk = 0; kk < 2; ++kk) {
      int cc = kk * 4 + kg;
      bf16x8 bfr[NFRAG];
#pragma unroll
      for (int fn = 0; fn < NFRAG; ++fn) {
        int rn = wid * 16 * NFRAG + fn * 16 + l15;
        bfr[fn] = *(const bf16x8*)&Bb[rn * 64 + ((cc ^ (rn & 7)) << 3)];
      }
#pragma unroll
      for (int fm = 0; fm < 2; ++fm) {
        int rm = fm * 16 + l15;
        bf16x8 afr = *(const bf16x8*)&Ab[rm * 64 + ((cc ^ (rm & 7)) << 3)];
#pragma unroll
        for (int fn = 0; fn < NFRAG; ++fn)
          acc[fm][fn] = __builtin_amdgcn_mfma_f32_16x16x32_bf16(afr, bfr[fn], acc[fm][fn], 0, 0, 0);
      }
    }
    cur ^= 1;
  }
#pragma unroll
  for (int fm = 0; fm < 2; ++fm) {
#pragma unroll
    for (int fn = 0; fn < NFRAG; ++fn) {
      int col = col0 + wid * 16 * NFRAG + fn * 16 + l15;
      float bi = bias[col];
      int rbase = row0 + fm * 16 + ((lane >> 4) << 2);
#pragma unroll
      for (int r = 0; r < 4; ++r) {
        int grow = rbase + r;
        float v = acc[fm][fn][r] + bi;
        if (ACT == 1) v = fmaxf(v, 0.f);
        if (OUT_BF16) Cb[(size_t)grow * N + col] = f2bu(v);
        else          Cf[(size_t)grow * N + col] = v;
      }
    }
  }
}

// x = LN(x + proj) * g + b  (+ bf16 shadow)
__global__ __launch_bounds__(256) void ln_residual_kernel(float* __restrict__ x, unsigned short* __restrict__ xbf,
                                                          const float* __restrict__ proj,
                                                          const float* __restrict__ g, const float* __restrict__ bb) {
  __shared__ float sred[4];
  int r = blockIdx.x, d = threadIdx.x;
  float v = x[(size_t)r * D_ + d] + proj[(size_t)r * D_ + d];
  float mean = block_reduce_sum_256(v, sred) * (1.f / 256.f);
  float dv = v - mean;
  float var = block_reduce_sum_256(dv * dv, sred) * (1.f / 256.f);
  float o = dv * (1.f / sqrtf(var + 1e-5f)) * g[d] + bb[d];
  x[(size_t)r * D_ + d] = o;
  xbf[(size_t)r * D_ + d] = f2bu(o);
}

// x[b,l,:] = tok[b*64+l,:], x[b,64,:] = sum_l tok ; also bf16 shadow
__global__ void build_x_kernel(const float* __restrict__ tok, float* __restrict__ x,
                               unsigned short* __restrict__ xbf) {
  int b = blockIdx.x, d = threadIdx.x;
  float s = 0.f;
  for (int l = 0; l < L_; ++l) {
    float v = tok[((size_t)(b * L_ + l)) * D_ + d];
    size_t o = ((size_t)(b * T_ + l)) * D_ + d;
    x[o] = v; xbf[o] = f2bu(v);
    s += v;
  }
  size_t o = ((size_t)(b * T_ + L_)) * D_ + d;
  x[o] = s; xbf[o] = f2bu(s);
}

// ---------------- attention (2-way Q-row split; bf16 I/O, fp32 math) ----------------
__global__ __launch_bounds__(256) void attn_kernel(const unsigned short* __restrict__ qkv,
                                                   unsigned short* __restrict__ attn_out) {
  int bid = blockIdx.x;               // 512 blocks: (b,h,half)
  int half = bid & 1;
  int bh = bid >> 1;
  int b = bh >> 3, h = bh & 7;
  int t0 = half ? 33 : 0;
  int nrows = half ? 32 : 33;
  __shared__ float Q[33][32], K[T_][32], V[T_][32];
  __shared__ float Sc[33][T_ + 1];
  int tid = threadIdx.x;
  for (int idx = tid; idx < T_ * 32; idx += 256) {
    int t = idx >> 5, d = idx & 31;
    const unsigned short* base = qkv + ((size_t)(b * T_ + t)) * 768 + h * 32 + d;
    K[t][d] = b2f(base[256]);
    V[t][d] = b2f(base[512]);
    if (t >= t0 && t < t0 + nrows) Q[t - t0][d] = b2f(base[0]);
  }
  __syncthreads();
  for (int idx = tid; idx < nrows * T_; idx += 256) {
    int qi = idx / T_, ki = idx % T_;
    float s = 0.f;
#pragma unroll
    for (int d = 0; d < 32; ++d) s += Q[qi][d] * K[ki][d];
    Sc[qi][ki] = s * 0.17677669529663687f;
  }
  __syncthreads();
  {
    int q = tid & 3;
    for (int row = tid >> 2; row < nrows; row += 64) {
      float mx = -1e30f;
      for (int k = q; k < T_; k += 4) mx = fmaxf(mx, Sc[row][k]);
      mx = fmaxf(mx, __shfl_xor(mx, 1, 64));
      mx = fmaxf(mx, __shfl_xor(mx, 2, 64));
      float sum = 0.f;
      for (int k = q; k < T_; k += 4) { float e = expf(Sc[row][k] - mx); Sc[row][k] = e; sum += e; }
      sum += __shfl_xor(sum, 1, 64);
      sum += __shfl_xor(sum, 2, 64);
      float inv = 1.f / sum;
      for (int k = q; k < T_; k += 4) Sc[row][k] *= inv;
    }
  }
  __syncthreads();
  for (int idx = tid; idx < nrows * 32; idx += 256) {
    int t = idx >> 5, d = idx & 31;
    float acc = 0.f;
    for (int k = 0; k < T_; ++k) acc += Sc[t][k] * V[k][d];
    attn_out[((size_t)(b * T_ + t0 + t)) * D_ + h * 32 + d] = f2bu(acc);
  }
}

// ---------------- capsule routing ----------------
__global__ __launch_bounds__(256) void cws_kernel(const float* __restrict__ x, const float* __restrict__ w_route,
                                                  const float* __restrict__ w_act, float* __restrict__ c_ws_out,
                                                  float* __restrict__ a_words) {
  int bl = blockIdx.x;
  int b = bl >> 6, l = bl & 63;
  __shared__ float word[256];
  __shared__ float logits[16];
  __shared__ float sred[4];
  int t = threadIdx.x;
  word[t] = x[((size_t)(b * T_ + l)) * D_ + t];
  __syncthreads();
  float pa = word[t] * w_act[t];
  float asum = block_reduce_sum_256(pa, sred);
  if (t == 0) a_words[b * 64 + l] = 1.f / (1.f + expf(-asum));
  int s = t >> 4, j0 = t & 15;
  float p = 0.f;
  for (int j = j0; j < 256; j += 16) p += w_route[((size_t)(l * 16 + s)) * 256 + j] * word[j];
#pragma unroll
  for (int m = 8; m >= 1; m >>= 1) p += __shfl_xor(p, m, 64);
  if (j0 == 0) logits[s] = p;
  __syncthreads();
  if (t < 16) {
    float mx = -1e30f;
#pragma unroll
    for (int k = 0; k < 16; ++k) mx = fmaxf(mx, logits[k]);
    float sum = 0.f;
#pragma unroll
    for (int k = 0; k < 16; ++k) sum += expf(logits[k] - mx);
    c_ws_out[(size_t)bl * 16 + t] = expf(logits[t] - mx) / sum;
  }
}

__global__ __launch_bounds__(64) void slot_agg_kernel(const float* __restrict__ c_ws, const float* __restrict__ a_words,
                                                      float* __restrict__ a_num, float* __restrict__ a_slots,
                                                      float* __restrict__ asl_sum) {
  int b = blockIdx.x, lane = threadIdx.x;
  float aw = a_words[b * 64 + lane];
  float asum = wave_reduce_sum(aw);
  float inv = 1.f / asum;
  float ssum = 0.f;
  for (int s = 0; s < 16; ++s) {
    float p = c_ws[((size_t)(b * 64 + lane)) * 16 + s] * aw;
    float r = wave_reduce_sum(p);
    if (lane == 0) {
      a_num[b * 16 + s] = r;
      a_slots[b * 16 + s] = r * inv;
      ssum += r * inv;
    }
  }
  if (lane == 0) asl_sum[b] = ssum;
}

// fused: bid<1024 -> pose_ws (2-stage reg prefetch); else pose_si partial
__global__ __launch_bounds__(256, 4) void pose_fused_kernel(const unsigned short* __restrict__ xbf,
                                                            const float* __restrict__ P,
                                                            const float* __restrict__ c_ws,
                                                            const float* __restrict__ a_words,
                                                            float* __restrict__ partial,
                                                            const float* __restrict__ Psi,
                                                            float* __restrict__ R4) {
  int bid = blockIdx.x, tid = threadIdx.x;
  if (bid >= 1024) {
    // ---- pose_si partial: R4[jc][si][k] = sum of 64 j's ----
    int idx = bid - 1024;
    int si = idx >> 2, jc = idx & 3;
    int k = tid;
    const float* base = Psi + (size_t)si * 65536 + (size_t)jc * 64 * 256 + k;
    float a0 = 0.f, a1 = 0.f, a2 = 0.f, a3 = 0.f;
#pragma unroll
    for (int j = 0; j < 64; j += 4) {
      a0 += base[(j + 0) * 256];
      a1 += base[(j + 1) * 256];
      a2 += base[(j + 2) * 256];
      a3 += base[(j + 3) * 256];
    }
    R4[(size_t)jc * 65536 + si * 256 + k] = a0 + a1 + a2 + a3;
    return;
  }
  // ---- pose_ws: block (lg, s, ihalf); l = lg, lg+32; i in [ih*128, +128) ----
  int ih = bid & 1, s = (bid >> 1) & 15, lg = bid >> 5;
  int iBase = ih * 128;
  __shared__ __align__(16) unsigned short Bs[32 * 256];  // 16KB weighted words [b][k]
  int wid = tid >> 6, lane = tid & 63;
  int kg = lane >> 4, l15 = lane & 15;
  f32x4 acc[2][2];
#pragma unroll
  for (int i = 0; i < 2; ++i)
#pragma unroll
    for (int j = 0; j < 2; ++j) acc[i][j] = (f32x4){0.f, 0.f, 0.f, 0.f};

  int r0 = iBase + wid * 32 + l15;   // fm=0 row; fm=1 row = r0+16
#pragma unroll
  for (int li = 0; li < 2; ++li) {
    int l = lg + li * 32;
    __syncthreads();
    {
      int b = tid >> 3, c0 = (tid & 7) * 4;
      float w = c_ws[((size_t)(b * 64 + l)) * 16 + s] * a_words[b * 64 + l];
      const unsigned short* src = xbf + ((size_t)(b * T_ + l)) * D_;
#pragma unroll
      for (int j = 0; j < 4; ++j) {
        int c = c0 + j;
        union { float4 f4; unsigned short u[8]; } in, out;
        in.f4 = *(const float4*)(src + c * 8);
#pragma unroll
        for (int e = 0; e < 8; ++e) out.u[e] = f2bu(w * b2f(in.u[e]));
        *(float4*)&Bs[b * 256 + ((c ^ (b & 7)) << 3)] = out.f4;
      }
    }
    __syncthreads();
    const float* Pbase = P + (((size_t)(l * 16 + s)) << 16);
    const float* pr0 = Pbase + (size_t)r0 * 256 + kg * 8;
    const float* pr1 = pr0 + 16 * 256;
    // 2-stage pipeline over 8 steps: cc = 4*step+kg, kbase = 32*step (+kg*8 in ptr)
    float4 c00 = *(const float4*)(pr0);
    float4 c01 = *(const float4*)(pr0 + 4);
    float4 c10 = *(const float4*)(pr1);
    float4 c11 = *(const float4*)(pr1 + 4);
#pragma unroll
    for (int step = 0; step < 8; ++step) {
      float4 n00, n01, n10, n11;
      if (step < 7) {
        const float* q0 = pr0 + (step + 1) * 32;
        const float* q1 = pr1 + (step + 1) * 32;
        n00 = *(const float4*)(q0); n01 = *(const float4*)(q0 + 4);
        n10 = *(const float4*)(q1); n11 = *(const float4*)(q1 + 4);
      }
      int cc = 4 * step + kg;
      bf16x8 bfr[2];
#pragma unroll
      for (int fn = 0; fn < 2; ++fn) {
        int rb = fn * 16 + l15;
        bfr[fn] = *(const bf16x8*)&Bs[rb * 256 + ((cc ^ (rb & 7)) << 3)];
      }
      union { bf16x8 b8; unsigned short u[8]; } pk0, pk1;
      pk0.u[0] = f2bu(c00.x); pk0.u[1] = f2bu(c00.y); pk0.u[2] = f2bu(c00.z); pk0.u[3] = f2bu(c00.w);
      pk0.u[4] = f2bu(c01.x); pk0.u[5] = f2bu(c01.y); pk0.u[6] = f2bu(c01.z); pk0.u[7] = f2bu(c01.w);
      pk1.u[0] = f2bu(c10.x); pk1.u[1] = f2bu(c10.y); pk1.u[2] = f2bu(c10.z); pk1.u[3] = f2bu(c10.w);
      pk1.u[4] = f2bu(c11.x); pk1.u[5] = f2bu(c11.y); pk1.u[6] = f2bu(c11.z); pk1.u[7] = f2bu(c11.w);
      acc[0][0] = __builtin_amdgcn_mfma_f32_16x16x32_bf16(pk0.b8, bfr[0], acc[0][0], 0, 0, 0);
      acc[0][1] = __builtin_amdgcn_mfma_f32_16x16x32_bf16(pk0.b8, bfr[1], acc[0][1], 0, 0, 0);
      acc[1][0] = __builtin_amdgcn_mfma_f32_16x16x32_bf16(pk1.b8, bfr[0], acc[1][0], 0, 0, 0);
      acc[1][1] = __builtin_amdgcn_mfma_f32_16x16x32_bf16(pk1.b8, bfr[1], acc[1][1], 0, 0, 0);
      c00 = n00; c01 = n01; c10 = n10; c11 = n11;
    }
  }
  float* pout = partial + ((size_t)(lg * 16 + s)) * 8192;
#pragma unroll
  for (int fm = 0; fm < 2; ++fm) {
#pragma unroll
    for (int fn = 0; fn < 2; ++fn) {
      int b = fn * 16 + l15;
      int i0 = iBase + wid * 32 + fm * 16 + (kg << 2);
#pragma unroll
      for (int r = 0; r < 4; ++r)
        pout[(i0 + r) * 32 + b] = acc[fm][fn][r];
    }
  }
}

// u_slots[(b*16+s)*256+i] = (sum_lg partial[(lg*16+s)][i*32+b]) / a_num[b*16+s]
__global__ __launch_bounds__(256) void reduce_uslots_kernel(const float* __restrict__ partial,
                                                            const float* __restrict__ a_num,
                                                            float* __restrict__ u_slots) {
  int s = blockIdx.x >> 5, ic = blockIdx.x & 31;
  int t = threadIdx.x;
  int i = ic * 8 + (t >> 5), b = t & 31;
  size_t off = (size_t)s * 8192 + i * 32 + b;
  float a0 = 0.f, a1 = 0.f, a2 = 0.f, a3 = 0.f;
#pragma unroll
  for (int lg = 0; lg < 32; lg += 4) {
    a0 += partial[((size_t)(lg + 0) * 16) * 8192 + off];
    a1 += partial[((size_t)(lg + 1) * 16) * 8192 + off];
    a2 += partial[((size_t)(lg + 2) * 16) * 8192 + off];
    a3 += partial[((size_t)(lg + 3) * 16) * 8192 + off];
  }
  u_slots[((size_t)(b * 16 + s)) * 256 + i] = (a0 + a1 + a2 + a3) / a_num[b * 16 + s];
}

// fused capsule tail: csi softmax + an/argmax + u_pose + cls head + LN  (one block per b)
__global__ __launch_bounds__(256) void cap_tail_kernel(const float* __restrict__ u_slots,
                                                       const float* __restrict__ a_slots,
                                                       const float* __restrict__ w_route_si,
                                                       const float* __restrict__ R4,
                                                       const float* __restrict__ x,
                                                       const float* __restrict__ cls_w,
                                                       const float* __restrict__ cls_b,
                                                       const float* __restrict__ g,
                                                       const float* __restrict__ bb,
                                                       float* __restrict__ out) {
  int b = blockIdx.x, t = threadIdx.x;
  __shared__ float us[16][256];
  __shared__ float lg_s[16][17];
  __shared__ float asl_s[16], an_s[16], w_s[16];
  __shared__ float row[512];
  __shared__ float part[256];
  __shared__ float sredx[4];
  __shared__ float an_star_s;
  __shared__ int istar_s;
#pragma unroll
  for (int p = 0; p < 16; ++p) us[p][t] = u_slots[((size_t)(b * 16 + p)) * 256 + t];
  if (t < 16) asl_s[t] = a_slots[b * 16 + t];
  __syncthreads();
  // csi logits
  int i4 = t >> 4, j0 = t & 15;
  for (int s = 0; s < 16; ++s) {
    float p = 0.f;
    for (int j = j0; j < 256; j += 16) p += w_route_si[((size_t)(s * 16 + i4)) * 256 + j] * us[s][j];
#pragma unroll
    for (int m = 8; m >= 1; m >>= 1) p += __shfl_xor(p, m, 64);
    if (j0 == 0) lg_s[s][i4] = p;
  }
  __syncthreads();
  if (t < 16) {  // softmax over i for s=t
    float mx = -1e30f;
#pragma unroll
    for (int i = 0; i < 16; ++i) mx = fmaxf(mx, lg_s[t][i]);
    float sum = 0.f;
#pragma unroll
    for (int i = 0; i < 16; ++i) { float e = expf(lg_s[t][i] - mx); lg_s[t][i] = e; sum += e; }
    float inv = 1.f / sum;
#pragma unroll
    for (int i = 0; i < 16; ++i) lg_s[t][i] *= inv;
  }
  __syncthreads();
  if (t < 16) {
    float a = 0.f;
#pragma unroll
    for (int s = 0; s < 16; ++s) a += lg_s[s][t] * asl_s[s];
    an_s[t] = a;
  }
  __syncthreads();
  if (t == 0) {
    int best = 0; float bv = an_s[0];
#pragma unroll
    for (int k = 1; k < 16; ++k)
      if (an_s[k] > bv) { bv = an_s[k]; best = k; }
    istar_s = best; an_star_s = bv;
  }
  __syncthreads();
  int istar = istar_s;
  if (t < 16) w_s[t] = lg_s[t][istar] * asl_s[t];
  __syncthreads();
  {
    float acc = 0.f;
#pragma unroll
    for (int s = 0; s < 16; ++s) {
      size_t ro = ((size_t)(s * 16 + istar)) * 256 + t;
      float r = R4[ro] + R4[65536 + ro] + R4[131072 + ro] + R4[196608 + ro];
      acc += w_s[s] * r * us[s][t];
    }
    row[256 + t] = acc / (an_star_s + 1e-8f);
    row[t] = x[((size_t)(b * T_ + L_)) * D_ + t];
  }
  __syncthreads();
  // cls head: output m = t&127, half = t>>7 sums 256 of the 512
  {
    int m = t & 127, hf = t >> 7;
    const float* wr = cls_w + (size_t)m * 512 + hf * 256;
    const float* rr = &row[hf * 256];
    float acc = 0.f;
    for (int j = 0; j < 256; ++j) acc += wr[j] * rr[j];
    part[t] = acc;
  }
  __syncthreads();
  float a = (t < 128) ? part[t] + part[t + 128] + cls_b[t] : 0.f;
  float v = wave_reduce_sum(a);
  if ((t & 63) == 0) sredx[t >> 6] = v;
  __syncthreads();
  float mean = (sredx[0] + sredx[1] + sredx[2] + sredx[3]) * (1.f / 128.f);
  float dv = a - mean;
  float q = (t < 128) ? dv * dv : 0.f;
  float v2 = wave_reduce_sum(q);
  if ((t & 63) == 0) sredx[t >> 6] = v2;
  __syncthreads();
  float var = (sredx[0] + sredx[1] + sredx[2] + sredx[3]) * (1.f / 128.f);
  if (t < 128)
    out[(size_t)b * 128 + t] = dv * (1.f / sqrtf(var + 1e-5f)) * g[t] + bb[t];
}

extern "C" void kernel_launch(void* const* d_in, const int* in_sizes, int n_in,
                              void* d_out, int out_size, void* d_ws, size_t ws_size,
                              hipStream_t stream) {
  (void)in_sizes; (void)n_in; (void)out_size; (void)ws_size;
  const float* dense      = (const float*)d_in[0];
  const float* sparse     = (const float*)d_in[1];
  const float* W_feat     = (const float*)d_in[2];
  const float* b_feat     = (const float*)d_in[3];
  const float* in_proj_w  = (const float*)d_in[4];
  const float* in_proj_b  = (const float*)d_in[5];
  const float* out_w      = (const float*)d_in[6];
  const float* out_b      = (const float*)d_in[7];
  const float* ln1_g      = (const float*)d_in[8];
  const float* ln1_b      = (const float*)d_in[9];
  const float* ln2_g      = (const float*)d_in[10];
  const float* ln2_b      = (const float*)d_in[11];
  const float* ff1_w      = (const float*)d_in[12];
  const float* ff1_b      = (const float*)d_in[13];
  const float* ff2_w      = (const float*)d_in[14];
  const float* ff2_b      = (const float*)d_in[15];
  const float* w_act      = (const float*)d_in[16];
  const float* w_route_ws = (const float*)d_in[17];
  const float* w_pose_ws  = (const float*)d_in[18];
  const float* w_route_si = (const float*)d_in[19];
  const float* w_pose_si  = (const float*)d_in[20];
  const float* cls_w      = (const float*)d_in[21];
  const float* cls_b      = (const float*)d_in[22];
  const float* inorm_g    = (const float*)d_in[23];
  const float* inorm_b    = (const float*)d_in[24];

  float* ws = (float*)d_ws;
  float* X       = ws;                 // 532480
  float* PROJ    = X + 532480;         // 532480
  float* a_words = PROJ + 532480;      // 2048
  float* a_num   = a_words + 2048;     // 512
  float* a_slots = a_num + 512;        // 512
  float* asl_sum = a_slots + 512;      // 32
  float* u_slots = asl_sum + 32;       // 131072
  float* R4      = u_slots + 131072;   // 262144

  unsigned short* bfb   = (unsigned short*)(R4 + 262144);
  unsigned short* Xbf   = bfb;                   // 532480
  unsigned short* QKVbf = Xbf + 532480;          // 1597440
  unsigned short* HAR   = QKVbf + 1597440;       // 4259840 (H; also CATbf, ATTNbf)
  unsigned short* CATbf = HAR;                   // 524288
  unsigned short* ATTNbf= HAR + 2097152;         // 532480
  unsigned short* wfeatT= HAR + 4259840;         // 65536
  unsigned short* ipwB  = wfeatT + 65536;        // 393216
  unsigned short* owB   = ipwB + 393216;         // 131072
  unsigned short* f1wB  = owB + 131072;          // 1048576
  unsigned short* f2wB  = f1wB + 1048576;        // 1048576
  // pose partials (16.78MB) reuse the then-dead bf16 arena from QKVbf on
  float* partial = (float*)QKVbf;

  float* c_ws_out    = (float*)d_out;          // 32768
  float* intents_out = (float*)d_out + 32768;  // 4096

  // converters (one launch)
  conv_fused_kernel<<<4624, 256, 0, stream>>>(dense, sparse, CATbf, W_feat, wfeatT,
                                              in_proj_w, out_w, ff1_w, ff2_w,
                                              ipwB, owB, f1wB, f2wB);

  // featurizer
  gemm_bf2_kernel<0, 0, 1><<<dim3(4, 64), 256, 0, stream>>>(CATbf, wfeatT, b_feat, PROJ, nullptr, 2048, 256, 256);
  build_x_kernel<<<32, 256, 0, stream>>>(PROJ, X, Xbf);

  for (int layer = 0; layer < 2; ++layer) {
    const unsigned short* ipw = ipwB + (size_t)layer * 196608;
    const unsigned short* ow  = owB + (size_t)layer * 65536;
    const unsigned short* f1w = f1wB + (size_t)layer * 524288;
    const unsigned short* f2w = f2wB + (size_t)layer * 524288;
    const float* ipb = in_proj_b + (size_t)layer * 768;
    const float* ob  = out_b + (size_t)layer * 256;
    const float* g1  = ln1_g + (size_t)layer * 256;
    const float* b1  = ln1_b + (size_t)layer * 256;
    const float* g2  = ln2_g + (size_t)layer * 256;
    const float* b2  = ln2_b + (size_t)layer * 256;
    const float* f1b = ff1_b + (size_t)layer * DFF_;
    const float* f2b = ff2_b + (size_t)layer * 256;

    gemm_bf2_kernel<0, 1, 2><<<dim3(6, 65), 256, 0, stream>>>(Xbf, ipw, ipb, nullptr, QKVbf, NT_, 768, 256);
    attn_kernel<<<B_ * H_ * 2, 256, 0, stream>>>(QKVbf, ATTNbf);
    gemm_bf2_kernel<0, 0, 1><<<dim3(4, 65), 256, 0, stream>>>(ATTNbf, ow, ob, PROJ, nullptr, NT_, 256, 256);
    ln_residual_kernel<<<NT_, 256, 0, stream>>>(X, Xbf, PROJ, g1, b1);
    gemm_bf2_kernel<1, 1, 2><<<dim3(16, 65), 256, 0, stream>>>(Xbf, f1w, f1b, nullptr, HAR, NT_, DFF_, 256);
    gemm_bf2_kernel<0, 0, 1><<<dim3(4, 65), 256, 0, stream>>>(HAR, f2w, f2b, PROJ, nullptr, NT_, 256, 2048);
    ln_residual_kernel<<<NT_, 256, 0, stream>>>(X, Xbf, PROJ, g2, b2);
  }

  // capsule routing
  cws_kernel<<<2048, 256, 0, stream>>>(X, w_route_ws, w_act, c_ws_out, a_words);
  slot_agg_kernel<<<32, 64, 0, stream>>>(c_ws_out, a_words, a_num, a_slots, asl_sum);
  pose_fused_kernel<<<2048, 256, 0, stream>>>(Xbf, w_pose_ws, c_ws_out, a_words, partial,
                                              w_pose_si, R4);
  reduce_uslots_kernel<<<512, 256, 0, stream>>>(partial, a_num, u_slots);
  cap_tail_kernel<<<32, 256, 0, stream>>>(u_slots, a_slots, w_route_si, R4, X,
                                          cls_w, cls_b, inorm_g, inorm_b, intents_out);
}

// Round 10
// 307.572 us; speedup vs baseline: 1.0314x; 1.0314x over previous
//
#include <hip/hip_runtime.h>
#include <hip/hip_bf16.h>
#include <math.h>

// dims
#define B_ 32
#define L_ 64
#define D_ 256
#define H_ 8
#define T_ 65
#define NT_ (B_*T_)   // 2080
#define DFF_ 2048
#define S_ 16
#define I_ 16
#define DSEM_ 128

typedef __attribute__((ext_vector_type(8))) short bf16x8;
typedef __attribute__((ext_vector_type(4))) float f32x4;

typedef __attribute__((address_space(1))) const void gbl_void;
typedef __attribute__((address_space(3))) void lds_void;
#define GLOAD16(g, l) __builtin_amdgcn_global_load_lds((gbl_void*)(g), (lds_void*)(l), 16, 0, 0)

__device__ inline unsigned short f2bu(float f) {
  union { float f; unsigned u; } a; a.f = f;
  unsigned r = a.u + 0x7FFF + ((a.u >> 16) & 1);
  return (unsigned short)(r >> 16);
}
__device__ inline float b2f(unsigned short u) {
  union { unsigned u; float f; } a; a.u = ((unsigned)u) << 16;
  return a.f;
}

__device__ inline float wave_reduce_sum(float v) {
#pragma unroll
  for (int m = 32; m >= 1; m >>= 1) v += __shfl_xor(v, m, 64);
  return v;
}

__device__ inline float block_reduce_sum_256(float v, float* sred) {
  v = wave_reduce_sum(v);
  int tid = threadIdx.x;
  if ((tid & 63) == 0) sred[tid >> 6] = v;
  __syncthreads();
  float r = sred[0] + sred[1] + sred[2] + sred[3];
  __syncthreads();
  return r;
}

// ---------------- fused converters (concat | W_feat transpose | 4x weight conv) ----------------
__global__ __launch_bounds__(256) void conv_fused_kernel(
    const float* __restrict__ dense, const float* __restrict__ sparse, unsigned short* __restrict__ cat,
    const float* __restrict__ wfeat, unsigned short* __restrict__ wfeatT,
    const float* __restrict__ ipw, const float* __restrict__ ow,
    const float* __restrict__ f1w, const float* __restrict__ f2w,
    unsigned short* __restrict__ ipwB, unsigned short* __restrict__ owB,
    unsigned short* __restrict__ f1wB, unsigned short* __restrict__ f2wB) {
  __shared__ float tb[64][65];
  int bid = blockIdx.x, tid = threadIdx.x;
  if (bid < 2048) {
    int idx = bid * 256 + tid;
    int r = idx >> 8, c = idx & 255;
    float v = (c < 128) ? dense[r * 128 + c] : sparse[r * 128 + (c - 128)];
    cat[idx] = f2bu(v);
  } else if (bid < 2064) {
    int blk = bid - 2048;
    int k0 = (blk & 3) * 64, n0 = (blk >> 2) * 64;
    int wid = tid >> 6, lane = tid & 63;
#pragma unroll
    for (int p = 0; p < 16; ++p)
      tb[p * 4 + wid][lane] = wfeat[(size_t)(k0 + p * 4 + wid) * 256 + n0 + lane];
    __syncthreads();
#pragma unroll
    for (int p = 0; p < 16; ++p)
      wfeatT[(size_t)(n0 + p * 4 + wid) * 256 + k0 + lane] = f2bu(tb[lane][p * 4 + wid]);
  } else {
    int i = (bid - 2064) * 256 + tid;  // over 655360 float4s
    const float* src; unsigned short* dst; int off;
    if (i < 98304)       { src = ipw; dst = ipwB; off = i; }
    else if (i < 131072) { src = ow;  dst = owB;  off = i - 98304; }
    else if (i < 393216) { src = f1w; dst = f1wB; off = i - 131072; }
    else                 { src = f2w; dst = f2wB; off = i - 393216; }
    float4 v = ((const float4*)src)[off];
    short4 o;
    o.x = (short)f2bu(v.x); o.y = (short)f2bu(v.y);
    o.z = (short)f2bu(v.z); o.w = (short)f2bu(v.w);
    ((short4*)dst)[off] = o;
  }
}

// ---------------- bf16 MFMA GEMM (NT): C[M,N] = act(A[M,K] @ W[N,K]^T + bias) ----------------
template <int ACT, int OUT_BF16, int NFRAG>
__global__ __launch_bounds__(256) void gemm_bf2_kernel(const unsigned short* __restrict__ A,
                                                       const unsigned short* __restrict__ W,
                                                       const float* __restrict__ bias,
                                                       float* __restrict__ Cf, unsigned short* __restrict__ Cb,
                                                       int M, int N, int K) {
  __shared__ __align__(16) unsigned short As[2][32 * 64];
  __shared__ __align__(16) unsigned short Bs[2][NFRAG * 64 * 64];
  int tid = threadIdx.x, wid = tid >> 6, lane = tid & 63;
  int row0 = blockIdx.y * 32, col0 = blockIdx.x * (64 * NFRAG);
  int lr = lane >> 3;
  int sc = ((lane & 7) ^ (lr & 7)) << 3;
  const unsigned short* Asrc = A + (size_t)(row0 + wid * 8 + lr) * K + sc;
  const unsigned short* Bsrc[2 * NFRAG];
#pragma unroll
  for (int p = 0; p < 2 * NFRAG; ++p)
    Bsrc[p] = W + (size_t)(col0 + wid * 16 * NFRAG + p * 8 + lr) * K + sc;
  unsigned short* AsW = &As[0][0] + wid * (8 * 64);
  unsigned short* BsW = &Bs[0][0] + wid * (16 * NFRAG * 64);

  f32x4 acc[2][NFRAG];
#pragma unroll
  for (int i = 0; i < 2; ++i)
#pragma unroll
    for (int j = 0; j < NFRAG; ++j) acc[i][j] = (f32x4){0.f, 0.f, 0.f, 0.f};

  GLOAD16(Asrc, AsW);
#pragma unroll
  for (int p = 0; p < 2 * NFRAG; ++p) GLOAD16(Bsrc[p], BsW + p * (8 * 64));

  int nk = K >> 6, cur = 0;
  int kg = lane >> 4, l15 = lane & 15;
  for (int kt = 0; kt < nk; ++kt) {
    __syncthreads();
    if (kt + 1 < nk) {
      int k0 = (kt + 1) << 6;
      GLOAD16(Asrc + k0, AsW + (cur ^ 1) * (32 * 64));
#pragma unroll
      for (int p = 0; p < 2 * NFRAG; ++p)
        GLOAD16(Bsrc[p] + k0, BsW + (cur ^ 1) * (NFRAG * 64 * 64) + p * (8 * 64));
    }
    const unsigned short* Ab = &As[cur][0];
    const unsigned short* Bb = &Bs[cur][0];
#pragma unroll
    for (int kk = 0; kk < 2; ++kk) {
      int cc = kk * 4 + kg;
      bf16x8 bfr[NFRAG];
#pragma unroll
      for (int fn = 0; fn < NFRAG; ++fn) {
        int rn = wid * 16 * NFRAG + fn * 16 + l15;
        bfr[fn] = *(const bf16x8*)&Bb[rn * 64 + ((cc ^ (rn & 7)) << 3)];
      }
#pragma unroll
      for (int fm = 0; fm < 2; ++fm) {
        int rm = fm * 16 + l15;
        bf16x8 afr = *(const bf16x8*)&Ab[rm * 64 + ((cc ^ (rm & 7)) << 3)];
#pragma unroll
        for (int fn = 0; fn < NFRAG; ++fn)
          acc[fm][fn] = __builtin_amdgcn_mfma_f32_16x16x32_bf16(afr, bfr[fn], acc[fm][fn], 0, 0, 0);
      }
    }
    cur ^= 1;
  }
#pragma unroll
  for (int fm = 0; fm < 2; ++fm) {
#pragma unroll
    for (int fn = 0; fn < NFRAG; ++fn) {
      int col = col0 + wid * 16 * NFRAG + fn * 16 + l15;
      float bi = bias[col];
      int rbase = row0 + fm * 16 + ((lane >> 4) << 2);
#pragma unroll
      for (int r = 0; r < 4; ++r) {
        int grow = rbase + r;
        float v = acc[fm][fn][r] + bi;
        if (ACT == 1) v = fmaxf(v, 0.f);
        if (OUT_BF16) Cb[(size_t)grow * N + col] = f2bu(v);
        else          Cf[(size_t)grow * N + col] = v;
      }
    }
  }
}

// x = LN(x + proj) * g + b  (+ bf16 shadow)
__global__ __launch_bounds__(256) void ln_residual_kernel(float* __restrict__ x, unsigned short* __restrict__ xbf,
                                                          const float* __restrict__ proj,
                                                          const float* __restrict__ g, const float* __restrict__ bb) {
  __shared__ float sred[4];
  int r = blockIdx.x, d = threadIdx.x;
  float v = x[(size_t)r * D_ + d] + proj[(size_t)r * D_ + d];
  float mean = block_reduce_sum_256(v, sred) * (1.f / 256.f);
  float dv = v - mean;
  float var = block_reduce_sum_256(dv * dv, sred) * (1.f / 256.f);
  float o = dv * (1.f / sqrtf(var + 1e-5f)) * g[d] + bb[d];
  x[(size_t)r * D_ + d] = o;
  xbf[(size_t)r * D_ + d] = f2bu(o);
}

// x[b,l,:] = tok[b*64+l,:], x[b,64,:] = sum_l tok ; also bf16 shadow
__global__ void build_x_kernel(const float* __restrict__ tok, float* __restrict__ x,
                               unsigned short* __restrict__ xbf) {
  int b = blockIdx.x, d = threadIdx.x;
  float s = 0.f;
  for (int l = 0; l < L_; ++l) {
    float v = tok[((size_t)(b * L_ + l)) * D_ + d];
    size_t o = ((size_t)(b * T_ + l)) * D_ + d;
    x[o] = v; xbf[o] = f2bu(v);
    s += v;
  }
  size_t o = ((size_t)(b * T_ + L_)) * D_ + d;
  x[o] = s; xbf[o] = f2bu(s);
}

// ---------------- attention (2-way Q-row split; bf16 I/O, fp32 math) ----------------
__global__ __launch_bounds__(256) void attn_kernel(const unsigned short* __restrict__ qkv,
                                                   unsigned short* __restrict__ attn_out) {
  int bid = blockIdx.x;               // 512 blocks: (b,h,half)
  int half = bid & 1;
  int bh = bid >> 1;
  int b = bh >> 3, h = bh & 7;
  int t0 = half ? 33 : 0;
  int nrows = half ? 32 : 33;
  __shared__ float Q[33][32], K[T_][32], V[T_][32];
  __shared__ float Sc[33][T_ + 1];
  int tid = threadIdx.x;
  for (int idx = tid; idx < T_ * 32; idx += 256) {
    int t = idx >> 5, d = idx & 31;
    const unsigned short* base = qkv + ((size_t)(b * T_ + t)) * 768 + h * 32 + d;
    K[t][d] = b2f(base[256]);
    V[t][d] = b2f(base[512]);
    if (t >= t0 && t < t0 + nrows) Q[t - t0][d] = b2f(base[0]);
  }
  __syncthreads();
  for (int idx = tid; idx < nrows * T_; idx += 256) {
    int qi = idx / T_, ki = idx % T_;
    float s = 0.f;
#pragma unroll
    for (int d = 0; d < 32; ++d) s += Q[qi][d] * K[ki][d];
    Sc[qi][ki] = s * 0.17677669529663687f;
  }
  __syncthreads();
  {
    int q = tid & 3;
    for (int row = tid >> 2; row < nrows; row += 64) {
      float mx = -1e30f;
      for (int k = q; k < T_; k += 4) mx = fmaxf(mx, Sc[row][k]);
      mx = fmaxf(mx, __shfl_xor(mx, 1, 64));
      mx = fmaxf(mx, __shfl_xor(mx, 2, 64));
      float sum = 0.f;
      for (int k = q; k < T_; k += 4) { float e = expf(Sc[row][k] - mx); Sc[row][k] = e; sum += e; }
      sum += __shfl_xor(sum, 1, 64);
      sum += __shfl_xor(sum, 2, 64);
      float inv = 1.f / sum;
      for (int k = q; k < T_; k += 4) Sc[row][k] *= inv;
    }
  }
  __syncthreads();
  for (int idx = tid; idx < nrows * 32; idx += 256) {
    int t = idx >> 5, d = idx & 31;
    float acc = 0.f;
    for (int k = 0; k < T_; ++k) acc += Sc[t][k] * V[k][d];
    attn_out[((size_t)(b * T_ + t0 + t)) * D_ + h * 32 + d] = f2bu(acc);
  }
}

// ---------------- capsule routing ----------------
__global__ __launch_bounds__(256) void cws_kernel(const float* __restrict__ x, const float* __restrict__ w_route,
                                                  const float* __restrict__ w_act, float* __restrict__ c_ws_out,
                                                  float* __restrict__ a_words) {
  int bl = blockIdx.x;
  int b = bl >> 6, l = bl & 63;
  __shared__ float word[256];
  __shared__ float logits[16];
  __shared__ float sred[4];
  int t = threadIdx.x;
  word[t] = x[((size_t)(b * T_ + l)) * D_ + t];
  __syncthreads();
  float pa = word[t] * w_act[t];
  float asum = block_reduce_sum_256(pa, sred);
  if (t == 0) a_words[b * 64 + l] = 1.f / (1.f + expf(-asum));
  int s = t >> 4, j0 = t & 15;
  float p = 0.f;
  for (int j = j0; j < 256; j += 16) p += w_route[((size_t)(l * 16 + s)) * 256 + j] * word[j];
#pragma unroll
  for (int m = 8; m >= 1; m >>= 1) p += __shfl_xor(p, m, 64);
  if (j0 == 0) logits[s] = p;
  __syncthreads();
  if (t < 16) {
    float mx = -1e30f;
#pragma unroll
    for (int k = 0; k < 16; ++k) mx = fmaxf(mx, logits[k]);
    float sum = 0.f;
#pragma unroll
    for (int k = 0; k < 16; ++k) sum += expf(logits[k] - mx);
    c_ws_out[(size_t)bl * 16 + t] = expf(logits[t] - mx) / sum;
  }
}

__global__ __launch_bounds__(64) void slot_agg_kernel(const float* __restrict__ c_ws, const float* __restrict__ a_words,
                                                      float* __restrict__ a_num, float* __restrict__ a_slots,
                                                      float* __restrict__ asl_sum) {
  int b = blockIdx.x, lane = threadIdx.x;
  float aw = a_words[b * 64 + lane];
  float asum = wave_reduce_sum(aw);
  float inv = 1.f / asum;
  float ssum = 0.f;
  for (int s = 0; s < 16; ++s) {
    float p = c_ws[((size_t)(b * 64 + lane)) * 16 + s] * aw;
    float r = wave_reduce_sum(p);
    if (lane == 0) {
      a_num[b * 16 + s] = r;
      a_slots[b * 16 + s] = r * inv;
      ssum += r * inv;
    }
  }
  if (lane == 0) asl_sum[b] = ssum;
}

// fused: bid<1024 -> pose_ws (compiler-scheduled loads, R8 form); else pose_si partial
__global__ __launch_bounds__(256, 4) void pose_fused_kernel(const unsigned short* __restrict__ xbf,
                                                            const float* __restrict__ P,
                                                            const float* __restrict__ c_ws,
                                                            const float* __restrict__ a_words,
                                                            float* __restrict__ partial,
                                                            const float* __restrict__ Psi,
                                                            float* __restrict__ R4) {
  int bid = blockIdx.x, tid = threadIdx.x;
  if (bid >= 1024) {
    // ---- pose_si partial: R4[jc][si][k] = sum of 64 j's ----
    int idx = bid - 1024;
    int si = idx >> 2, jc = idx & 3;
    int k = tid;
    const float* base = Psi + (size_t)si * 65536 + (size_t)jc * 64 * 256 + k;
    float a0 = 0.f, a1 = 0.f, a2 = 0.f, a3 = 0.f;
#pragma unroll
    for (int j = 0; j < 64; j += 4) {
      a0 += base[(j + 0) * 256];
      a1 += base[(j + 1) * 256];
      a2 += base[(j + 2) * 256];
      a3 += base[(j + 3) * 256];
    }
    R4[(size_t)jc * 65536 + si * 256 + k] = a0 + a1 + a2 + a3;
    return;
  }
  // ---- pose_ws: block (lg, s, ihalf); l = lg, lg+32; i in [ih*128, +128) ----
  int ih = bid & 1, s = (bid >> 1) & 15, lg = bid >> 5;
  int iBase = ih * 128;
  __shared__ __align__(16) unsigned short Bs[32 * 256];  // 16KB weighted words [b][k]
  int wid = tid >> 6, lane = tid & 63;
  int kg = lane >> 4, l15 = lane & 15;
  f32x4 acc[2][2];
#pragma unroll
  for (int i = 0; i < 2; ++i)
#pragma unroll
    for (int j = 0; j < 2; ++j) acc[i][j] = (f32x4){0.f, 0.f, 0.f, 0.f};

#pragma unroll
  for (int li = 0; li < 2; ++li) {
    int l = lg + li * 32;
    __syncthreads();
    {
      int b = tid >> 3, c0 = (tid & 7) * 4;
      float w = c_ws[((size_t)(b * 64 + l)) * 16 + s] * a_words[b * 64 + l];
      const unsigned short* src = xbf + ((size_t)(b * T_ + l)) * D_;
#pragma unroll
      for (int j = 0; j < 4; ++j) {
        int c = c0 + j;
        union { float4 f4; unsigned short u[8]; } in, out;
        in.f4 = *(const float4*)(src + c * 8);
#pragma unroll
        for (int e = 0; e < 8; ++e) out.u[e] = f2bu(w * b2f(in.u[e]));
        *(float4*)&Bs[b * 256 + ((c ^ (b & 7)) << 3)] = out.f4;
      }
    }
    __syncthreads();
    const float* Pbase = P + (((size_t)(l * 16 + s)) << 16);
#pragma unroll
    for (int k0 = 0; k0 < 256; k0 += 64) {
#pragma unroll
      for (int kk = 0; kk < 2; ++kk) {
        int cc = (k0 >> 3) + kk * 4 + kg;
        bf16x8 bfr[2];
#pragma unroll
        for (int fn = 0; fn < 2; ++fn) {
          int rb = fn * 16 + l15;
          bfr[fn] = *(const bf16x8*)&Bs[rb * 256 + ((cc ^ (rb & 7)) << 3)];
        }
        int kbase = k0 + kk * 32 + kg * 8;
#pragma unroll
        for (int fm = 0; fm < 2; ++fm) {
          int row = iBase + wid * 32 + fm * 16 + l15;
          const float* src = Pbase + (size_t)row * 256 + kbase;
          float4 v0 = *(const float4*)src;
          float4 v1 = *(const float4*)(src + 4);
          union { bf16x8 b8; unsigned short u[8]; } pk;
          pk.u[0] = f2bu(v0.x); pk.u[1] = f2bu(v0.y); pk.u[2] = f2bu(v0.z); pk.u[3] = f2bu(v0.w);
          pk.u[4] = f2bu(v1.x); pk.u[5] = f2bu(v1.y); pk.u[6] = f2bu(v1.z); pk.u[7] = f2bu(v1.w);
          acc[fm][0] = __builtin_amdgcn_mfma_f32_16x16x32_bf16(pk.b8, bfr[0], acc[fm][0], 0, 0, 0);
          acc[fm][1] = __builtin_amdgcn_mfma_f32_16x16x32_bf16(pk.b8, bfr[1], acc[fm][1], 0, 0, 0);
        }
      }
    }
  }
  float* pout = partial + ((size_t)(lg * 16 + s)) * 8192;
#pragma unroll
  for (int fm = 0; fm < 2; ++fm) {
#pragma unroll
    for (int fn = 0; fn < 2; ++fn) {
      int b = fn * 16 + l15;
      int i0 = iBase + wid * 32 + fm * 16 + (kg << 2);
#pragma unroll
      for (int r = 0; r < 4; ++r)
        pout[(i0 + r) * 32 + b] = acc[fm][fn][r];
    }
  }
}

// u_slots[(b*16+s)*256+i] = (sum_lg partial[(lg*16+s)][i*32+b]) / a_num[b*16+s]
__global__ __launch_bounds__(256) void reduce_uslots_kernel(const float* __restrict__ partial,
                                                            const float* __restrict__ a_num,
                                                            float* __restrict__ u_slots) {
  int s = blockIdx.x >> 5, ic = blockIdx.x & 31;
  int t = threadIdx.x;
  int i = ic * 8 + (t >> 5), b = t & 31;
  size_t off = (size_t)s * 8192 + i * 32 + b;
  float a0 = 0.f, a1 = 0.f, a2 = 0.f, a3 = 0.f;
#pragma unroll
  for (int lg = 0; lg < 32; lg += 4) {
    a0 += partial[((size_t)(lg + 0) * 16) * 8192 + off];
    a1 += partial[((size_t)(lg + 1) * 16) * 8192 + off];
    a2 += partial[((size_t)(lg + 2) * 16) * 8192 + off];
    a3 += partial[((size_t)(lg + 3) * 16) * 8192 + off];
  }
  u_slots[((size_t)(b * 16 + s)) * 256 + i] = (a0 + a1 + a2 + a3) / a_num[b * 16 + s];
}

// fused capsule tail: csi softmax + an/argmax + u_pose + cls head + LN  (one block per b)
__global__ __launch_bounds__(256) void cap_tail_kernel(const float* __restrict__ u_slots,
                                                       const float* __restrict__ a_slots,
                                                       const float* __restrict__ w_route_si,
                                                       const float* __restrict__ R4,
                                                       const float* __restrict__ x,
                                                       const float* __restrict__ cls_w,
                                                       const float* __restrict__ cls_b,
                                                       const float* __restrict__ g,
                                                       const float* __restrict__ bb,
                                                       float* __restrict__ out) {
  int b = blockIdx.x, t = threadIdx.x;
  __shared__ float us[16][256];
  __shared__ float lg_s[16][17];
  __shared__ float asl_s[16], an_s[16], w_s[16];
  __shared__ float row[512];
  __shared__ float part[256];
  __shared__ float sredx[4];
  __shared__ float an_star_s;
  __shared__ int istar_s;
#pragma unroll
  for (int p = 0; p < 16; ++p) us[p][t] = u_slots[((size_t)(b * 16 + p)) * 256 + t];
  if (t < 16) asl_s[t] = a_slots[b * 16 + t];
  __syncthreads();
  // csi logits
  int i4 = t >> 4, j0 = t & 15;
  for (int s = 0; s < 16; ++s) {
    float p = 0.f;
    for (int j = j0; j < 256; j += 16) p += w_route_si[((size_t)(s * 16 + i4)) * 256 + j] * us[s][j];
#pragma unroll
    for (int m = 8; m >= 1; m >>= 1) p += __shfl_xor(p, m, 64);
    if (j0 == 0) lg_s[s][i4] = p;
  }
  __syncthreads();
  if (t < 16) {  // softmax over i for s=t
    float mx = -1e30f;
#pragma unroll
    for (int i = 0; i < 16; ++i) mx = fmaxf(mx, lg_s[t][i]);
    float sum = 0.f;
#pragma unroll
    for (int i = 0; i < 16; ++i) { float e = expf(lg_s[t][i] - mx); lg_s[t][i] = e; sum += e; }
    float inv = 1.f / sum;
#pragma unroll
    for (int i = 0; i < 16; ++i) lg_s[t][i] *= inv;
  }
  __syncthreads();
  if (t < 16) {
    float a = 0.f;
#pragma unroll
    for (int s = 0; s < 16; ++s) a += lg_s[s][t] * asl_s[s];
    an_s[t] = a;
  }
  __syncthreads();
  if (t == 0) {
    int best = 0; float bv = an_s[0];
#pragma unroll
    for (int k = 1; k < 16; ++k)
      if (an_s[k] > bv) { bv = an_s[k]; best = k; }
    istar_s = best; an_star_s = bv;
  }
  __syncthreads();
  int istar = istar_s;
  if (t < 16) w_s[t] = lg_s[t][istar] * asl_s[t];
  __syncthreads();
  {
    float acc = 0.f;
#pragma unroll
    for (int s = 0; s < 16; ++s) {
      size_t ro = ((size_t)(s * 16 + istar)) * 256 + t;
      float r = R4[ro] + R4[65536 + ro] + R4[131072 + ro] + R4[196608 + ro];
      acc += w_s[s] * r * us[s][t];
    }
    row[256 + t] = acc / (an_star_s + 1e-8f);
    row[t] = x[((size_t)(b * T_ + L_)) * D_ + t];
  }
  __syncthreads();
  // cls head: output m = t&127, half = t>>7 sums 256 of the 512
  {
    int m = t & 127, hf = t >> 7;
    const float* wr = cls_w + (size_t)m * 512 + hf * 256;
    const float* rr = &row[hf * 256];
    float acc = 0.f;
    for (int j = 0; j < 256; ++j) acc += wr[j] * rr[j];
    part[t] = acc;
  }
  __syncthreads();
  float a = (t < 128) ? part[t] + part[t + 128] + cls_b[t] : 0.f;
  float v = wave_reduce_sum(a);
  if ((t & 63) == 0) sredx[t >> 6] = v;
  __syncthreads();
  float mean = (sredx[0] + sredx[1] + sredx[2] + sredx[3]) * (1.f / 128.f);
  float dv = a - mean;
  float q = (t < 128) ? dv * dv : 0.f;
  float v2 = wave_reduce_sum(q);
  if ((t & 63) == 0) sredx[t >> 6] = v2;
  __syncthreads();
  float var = (sredx[0] + sredx[1] + sredx[2] + sredx[3]) * (1.f / 128.f);
  if (t < 128)
    out[(size_t)b * 128 + t] = dv * (1.f / sqrtf(var + 1e-5f)) * g[t] + bb[t];
}

extern "C" void kernel_launch(void* const* d_in, const int* in_sizes, int n_in,
                              void* d_out, int out_size, void* d_ws, size_t ws_size,
                              hipStream_t stream) {
  (void)in_sizes; (void)n_in; (void)out_size; (void)ws_size;
  const float* dense      = (const float*)d_in[0];
  const float* sparse     = (const float*)d_in[1];
  const float* W_feat     = (const float*)d_in[2];
  const float* b_feat     = (const float*)d_in[3];
  const float* in_proj_w  = (const float*)d_in[4];
  const float* in_proj_b  = (const float*)d_in[5];
  const float* out_w      = (const float*)d_in[6];
  const float* out_b      = (const float*)d_in[7];
  const float* ln1_g      = (const float*)d_in[8];
  const float* ln1_b      = (const float*)d_in[9];
  const float* ln2_g      = (const float*)d_in[10];
  const float* ln2_b      = (const float*)d_in[11];
  const float* ff1_w      = (const float*)d_in[12];
  const float* ff1_b      = (const float*)d_in[13];
  const float* ff2_w      = (const float*)d_in[14];
  const float* ff2_b      = (const float*)d_in[15];
  const float* w_act      = (const float*)d_in[16];
  const float* w_route_ws = (const float*)d_in[17];
  const float* w_pose_ws  = (const float*)d_in[18];
  const float* w_route_si = (const float*)d_in[19];
  const float* w_pose_si  = (const float*)d_in[20];
  const float* cls_w      = (const float*)d_in[21];
  const float* cls_b      = (const float*)d_in[22];
  const float* inorm_g    = (const float*)d_in[23];
  const float* inorm_b    = (const float*)d_in[24];

  float* ws = (float*)d_ws;
  float* X       = ws;                 // 532480
  float* PROJ    = X + 532480;         // 532480
  float* a_words = PROJ + 532480;      // 2048
  float* a_num   = a_words + 2048;     // 512
  float* a_slots = a_num + 512;        // 512
  float* asl_sum = a_slots + 512;      // 32
  float* u_slots = asl_sum + 32;       // 131072
  float* R4      = u_slots + 131072;   // 262144

  unsigned short* bfb   = (unsigned short*)(R4 + 262144);
  unsigned short* Xbf   = bfb;                   // 532480
  unsigned short* QKVbf = Xbf + 532480;          // 1597440
  unsigned short* HAR   = QKVbf + 1597440;       // 4259840 (H; also CATbf, ATTNbf)
  unsigned short* CATbf = HAR;                   // 524288
  unsigned short* ATTNbf= HAR + 2097152;         // 532480
  unsigned short* wfeatT= HAR + 4259840;         // 65536
  unsigned short* ipwB  = wfeatT + 65536;        // 393216
  unsigned short* owB   = ipwB + 393216;         // 131072
  unsigned short* f1wB  = owB + 131072;          // 1048576
  unsigned short* f2wB  = f1wB + 1048576;        // 1048576
  // pose partials (16.78MB) reuse the then-dead bf16 arena from QKVbf on
  float* partial = (float*)QKVbf;

  float* c_ws_out    = (float*)d_out;          // 32768
  float* intents_out = (float*)d_out + 32768;  // 4096

  // converters (one launch)
  conv_fused_kernel<<<4624, 256, 0, stream>>>(dense, sparse, CATbf, W_feat, wfeatT,
                                              in_proj_w, out_w, ff1_w, ff2_w,
                                              ipwB, owB, f1wB, f2wB);

  // featurizer
  gemm_bf2_kernel<0, 0, 1><<<dim3(4, 64), 256, 0, stream>>>(CATbf, wfeatT, b_feat, PROJ, nullptr, 2048, 256, 256);
  build_x_kernel<<<32, 256, 0, stream>>>(PROJ, X, Xbf);

  for (int layer = 0; layer < 2; ++layer) {
    const unsigned short* ipw = ipwB + (size_t)layer * 196608;
    const unsigned short* ow  = owB + (size_t)layer * 65536;
    const unsigned short* f1w = f1wB + (size_t)layer * 524288;
    const unsigned short* f2w = f2wB + (size_t)layer * 524288;
    const float* ipb = in_proj_b + (size_t)layer * 768;
    const float* ob  = out_b + (size_t)layer * 256;
    const float* g1  = ln1_g + (size_t)layer * 256;
    const float* b1  = ln1_b + (size_t)layer * 256;
    const float* g2  = ln2_g + (size_t)layer * 256;
    const float* b2  = ln2_b + (size_t)layer * 256;
    const float* f1b = ff1_b + (size_t)layer * DFF_;
    const float* f2b = ff2_b + (size_t)layer * 256;

    gemm_bf2_kernel<0, 1, 2><<<dim3(6, 65), 256, 0, stream>>>(Xbf, ipw, ipb, nullptr, QKVbf, NT_, 768, 256);
    attn_kernel<<<B_ * H_ * 2, 256, 0, stream>>>(QKVbf, ATTNbf);
    gemm_bf2_kernel<0, 0, 1><<<dim3(4, 65), 256, 0, stream>>>(ATTNbf, ow, ob, PROJ, nullptr, NT_, 256, 256);
    ln_residual_kernel<<<NT_, 256, 0, stream>>>(X, Xbf, PROJ, g1, b1);
    gemm_bf2_kernel<1, 1, 2><<<dim3(16, 65), 256, 0, stream>>>(Xbf, f1w, f1b, nullptr, HAR, NT_, DFF_, 256);
    gemm_bf2_kernel<0, 0, 1><<<dim3(4, 65), 256, 0, stream>>>(HAR, f2w, f2b, PROJ, nullptr, NT_, 256, 2048);
    ln_residual_kernel<<<NT_, 256, 0, stream>>>(X, Xbf, PROJ, g2, b2);
  }

  // capsule routing
  cws_kernel<<<2048, 256, 0, stream>>>(X, w_route_ws, w_act, c_ws_out, a_words);
  slot_agg_kernel<<<32, 64, 0, stream>>>(c_ws_out, a_words, a_num, a_slots, asl_sum);
  pose_fused_kernel<<<2048, 256, 0, stream>>>(Xbf, w_pose_ws, c_ws_out, a_words, partial,
                                              w_pose_si, R4);
  reduce_uslots_kernel<<<512, 256, 0, stream>>>(partial, a_num, u_slots);
  cap_tail_kernel<<<32, 256, 0, stream>>>(u_slots, a_slots, w_route_si, R4, X,
                                          cls_w, cls_b, inorm_g, inorm_b, intents_out);
}

// Round 11
// 280.647 us; speedup vs baseline: 1.1304x; 1.0959x over previous
//
#include <hip/hip_runtime.h>
#include <hip/hip_bf16.h>
#include <math.h>

// dims
#define B_ 32
#define L_ 64
#define D_ 256
#define H_ 8
#define T_ 65
#define NT_ (B_*T_)   // 2080
#define DFF_ 2048
#define S_ 16
#define I_ 16
#define DSEM_ 128

typedef __attribute__((ext_vector_type(8))) short bf16x8;
typedef __attribute__((ext_vector_type(4))) float f32x4;

typedef __attribute__((address_space(1))) const void gbl_void;
typedef __attribute__((address_space(3))) void lds_void;
#define GLOAD16(g, l) __builtin_amdgcn_global_load_lds((gbl_void*)(g), (lds_void*)(l), 16, 0, 0)

__device__ inline unsigned short f2bu(float f) {
  union { float f; unsigned u; } a; a.f = f;
  unsigned r = a.u + 0x7FFF + ((a.u >> 16) & 1);
  return (unsigned short)(r >> 16);
}
__device__ inline float b2f(unsigned short u) {
  union { unsigned u; float f; } a; a.u = ((unsigned)u) << 16;
  return a.f;
}

__device__ inline float wave_reduce_sum(float v) {
#pragma unroll
  for (int m = 32; m >= 1; m >>= 1) v += __shfl_xor(v, m, 64);
  return v;
}

__device__ inline float block_reduce_sum_256(float v, float* sred) {
  v = wave_reduce_sum(v);
  int tid = threadIdx.x;
  if ((tid & 63) == 0) sred[tid >> 6] = v;
  __syncthreads();
  float r = sred[0] + sred[1] + sred[2] + sred[3];
  __syncthreads();
  return r;
}

// ---------------- fused converters (concat | W_feat transpose | weight conv | pose_si partial) ----------------
__global__ __launch_bounds__(256) void conv_fused_kernel(
    const float* __restrict__ dense, const float* __restrict__ sparse, unsigned short* __restrict__ cat,
    const float* __restrict__ wfeat, unsigned short* __restrict__ wfeatT,
    const float* __restrict__ ipw, const float* __restrict__ ow,
    const float* __restrict__ f1w, const float* __restrict__ f2w,
    unsigned short* __restrict__ ipwB, unsigned short* __restrict__ owB,
    unsigned short* __restrict__ f1wB, unsigned short* __restrict__ f2wB,
    const float* __restrict__ Psi, float* __restrict__ R4) {
  __shared__ float tb[64][65];
  int bid = blockIdx.x, tid = threadIdx.x;
  if (bid < 2048) {
    int idx = bid * 256 + tid;
    int r = idx >> 8, c = idx & 255;
    float v = (c < 128) ? dense[r * 128 + c] : sparse[r * 128 + (c - 128)];
    cat[idx] = f2bu(v);
  } else if (bid < 2064) {
    int blk = bid - 2048;
    int k0 = (blk & 3) * 64, n0 = (blk >> 2) * 64;
    int wid = tid >> 6, lane = tid & 63;
#pragma unroll
    for (int p = 0; p < 16; ++p)
      tb[p * 4 + wid][lane] = wfeat[(size_t)(k0 + p * 4 + wid) * 256 + n0 + lane];
    __syncthreads();
#pragma unroll
    for (int p = 0; p < 16; ++p)
      wfeatT[(size_t)(n0 + p * 4 + wid) * 256 + k0 + lane] = f2bu(tb[lane][p * 4 + wid]);
  } else if (bid < 4624) {
    int i = (bid - 2064) * 256 + tid;  // over 655360 float4s
    const float* src; unsigned short* dst; int off;
    if (i < 98304)       { src = ipw; dst = ipwB; off = i; }
    else if (i < 131072) { src = ow;  dst = owB;  off = i - 98304; }
    else if (i < 393216) { src = f1w; dst = f1wB; off = i - 131072; }
    else                 { src = f2w; dst = f2wB; off = i - 393216; }
    float4 v = ((const float4*)src)[off];
    short4 o;
    o.x = (short)f2bu(v.x); o.y = (short)f2bu(v.y);
    o.z = (short)f2bu(v.z); o.w = (short)f2bu(v.w);
    ((short4*)dst)[off] = o;
  } else {
    // pose_si partial: R4[jc][si][k] = sum of 64 j's of w_pose_si[s,i,j,k]
    int idx = bid - 4624;              // 1024 blocks
    int si = idx >> 2, jc = idx & 3;
    int k = tid;
    const float* base = Psi + (size_t)si * 65536 + (size_t)jc * 64 * 256 + k;
    float a0 = 0.f, a1 = 0.f, a2 = 0.f, a3 = 0.f;
#pragma unroll
    for (int j = 0; j < 64; j += 4) {
      a0 += base[(j + 0) * 256];
      a1 += base[(j + 1) * 256];
      a2 += base[(j + 2) * 256];
      a3 += base[(j + 3) * 256];
    }
    R4[(size_t)jc * 65536 + si * 256 + k] = a0 + a1 + a2 + a3;
  }
}

// ---------------- bf16 MFMA GEMM (NT): C[M,N] = act(A[M,K] @ W[N,K]^T + bias) ----------------
template <int ACT, int OUT_BF16, int NFRAG>
__global__ __launch_bounds__(256) void gemm_bf2_kernel(const unsigned short* __restrict__ A,
                                                       const unsigned short* __restrict__ W,
                                                       const float* __restrict__ bias,
                                                       float* __restrict__ Cf, unsigned short* __restrict__ Cb,
                                                       int M, int N, int K) {
  __shared__ __align__(16) unsigned short As[2][32 * 64];
  __shared__ __align__(16) unsigned short Bs[2][NFRAG * 64 * 64];
  int tid = threadIdx.x, wid = tid >> 6, lane = tid & 63;
  int row0 = blockIdx.y * 32, col0 = blockIdx.x * (64 * NFRAG);
  int lr = lane >> 3;
  int sc = ((lane & 7) ^ (lr & 7)) << 3;
  const unsigned short* Asrc = A + (size_t)(row0 + wid * 8 + lr) * K + sc;
  const unsigned short* Bsrc[2 * NFRAG];
#pragma unroll
  for (int p = 0; p < 2 * NFRAG; ++p)
    Bsrc[p] = W + (size_t)(col0 + wid * 16 * NFRAG + p * 8 + lr) * K + sc;
  unsigned short* AsW = &As[0][0] + wid * (8 * 64);
  unsigned short* BsW = &Bs[0][0] + wid * (16 * NFRAG * 64);

  f32x4 acc[2][NFRAG];
#pragma unroll
  for (int i = 0; i < 2; ++i)
#pragma unroll
    for (int j = 0; j < NFRAG; ++j) acc[i][j] = (f32x4){0.f, 0.f, 0.f, 0.f};

  GLOAD16(Asrc, AsW);
#pragma unroll
  for (int p = 0; p < 2 * NFRAG; ++p) GLOAD16(Bsrc[p], BsW + p * (8 * 64));

  int nk = K >> 6, cur = 0;
  int kg = lane >> 4, l15 = lane & 15;
  for (int kt = 0; kt < nk; ++kt) {
    __syncthreads();
    if (kt + 1 < nk) {
      int k0 = (kt + 1) << 6;
      GLOAD16(Asrc + k0, AsW + (cur ^ 1) * (32 * 64));
#pragma unroll
      for (int p = 0; p < 2 * NFRAG; ++p)
        GLOAD16(Bsrc[p] + k0, BsW + (cur ^ 1) * (NFRAG * 64 * 64) + p * (8 * 64));
    }
    const unsigned short* Ab = &As[cur][0];
    const unsigned short* Bb = &Bs[cur][0];
#pragma unroll
    for (int kk = 0; kk < 2; ++kk) {
      int cc = kk * 4 + kg;
      bf16x8 bfr[NFRAG];
#pragma unroll
      for (int fn = 0; fn < NFRAG; ++fn) {
        int rn = wid * 16 * NFRAG + fn * 16 + l15;
        bfr[fn] = *(const bf16x8*)&Bb[rn * 64 + ((cc ^ (rn & 7)) << 3)];
      }
#pragma unroll
      for (int fm = 0; fm < 2; ++fm) {
        int rm = fm * 16 + l15;
        bf16x8 afr = *(const bf16x8*)&Ab[rm * 64 + ((cc ^ (rm & 7)) << 3)];
#pragma unroll
        for (int fn = 0; fn < NFRAG; ++fn)
          acc[fm][fn] = __builtin_amdgcn_mfma_f32_16x16x32_bf16(afr, bfr[fn], acc[fm][fn], 0, 0, 0);
      }
    }
    cur ^= 1;
  }
#pragma unroll
  for (int fm = 0; fm < 2; ++fm) {
#pragma unroll
    for (int fn = 0; fn < NFRAG; ++fn) {
      int col = col0 + wid * 16 * NFRAG + fn * 16 + l15;
      float bi = bias[col];
      int rbase = row0 + fm * 16 + ((lane >> 4) << 2);
#pragma unroll
      for (int r = 0; r < 4; ++r) {
        int grow = rbase + r;
        float v = acc[fm][fn][r] + bi;
        if (ACT == 1) v = fmaxf(v, 0.f);
        if (OUT_BF16) Cb[(size_t)grow * N + col] = f2bu(v);
        else          Cf[(size_t)grow * N + col] = v;
      }
    }
  }
}

// x = LN(x + proj) * g + b  (+ bf16 shadow)
__global__ __launch_bounds__(256) void ln_residual_kernel(float* __restrict__ x, unsigned short* __restrict__ xbf,
                                                          const float* __restrict__ proj,
                                                          const float* __restrict__ g, const float* __restrict__ bb) {
  __shared__ float sred[4];
  int r = blockIdx.x, d = threadIdx.x;
  float v = x[(size_t)r * D_ + d] + proj[(size_t)r * D_ + d];
  float mean = block_reduce_sum_256(v, sred) * (1.f / 256.f);
  float dv = v - mean;
  float var = block_reduce_sum_256(dv * dv, sred) * (1.f / 256.f);
  float o = dv * (1.f / sqrtf(var + 1e-5f)) * g[d] + bb[d];
  x[(size_t)r * D_ + d] = o;
  xbf[(size_t)r * D_ + d] = f2bu(o);
}

// x[b,l,:] = tok[b*64+l,:], x[b,64,:] = sum_l tok ; also bf16 shadow
__global__ void build_x_kernel(const float* __restrict__ tok, float* __restrict__ x,
                               unsigned short* __restrict__ xbf) {
  int b = blockIdx.x, d = threadIdx.x;
  float s = 0.f;
  for (int l = 0; l < L_; ++l) {
    float v = tok[((size_t)(b * L_ + l)) * D_ + d];
    size_t o = ((size_t)(b * T_ + l)) * D_ + d;
    x[o] = v; xbf[o] = f2bu(v);
    s += v;
  }
  size_t o = ((size_t)(b * T_ + L_)) * D_ + d;
  x[o] = s; xbf[o] = f2bu(s);
}

// ---------------- attention (bf16 I/O, fp32 math, wave-parallel softmax) ----------------
__global__ __launch_bounds__(256) void attn_kernel(const unsigned short* __restrict__ qkv,
                                                   unsigned short* __restrict__ attn_out) {
  int bh = blockIdx.x;
  int b = bh >> 3, h = bh & 7;
  __shared__ float Q[T_][32], K[T_][32], V[T_][32];
  __shared__ float Sc[T_][T_ + 1];
  int tid = threadIdx.x;
  for (int idx = tid; idx < T_ * 32; idx += 256) {
    int t = idx >> 5, d = idx & 31;
    const unsigned short* base = qkv + ((size_t)(b * T_ + t)) * 768 + h * 32 + d;
    Q[t][d] = b2f(base[0]);
    K[t][d] = b2f(base[256]);
    V[t][d] = b2f(base[512]);
  }
  __syncthreads();
  for (int idx = tid; idx < T_ * T_; idx += 256) {
    int qi = idx / T_, ki = idx % T_;
    float s = 0.f;
#pragma unroll
    for (int d = 0; d < 32; ++d) s += Q[qi][d] * K[ki][d];
    Sc[qi][ki] = s * 0.17677669529663687f;
  }
  __syncthreads();
  {
    int q = tid & 3;
    for (int row = tid >> 2; row < T_; row += 64) {
      float mx = -1e30f;
      for (int k = q; k < T_; k += 4) mx = fmaxf(mx, Sc[row][k]);
      mx = fmaxf(mx, __shfl_xor(mx, 1, 64));
      mx = fmaxf(mx, __shfl_xor(mx, 2, 64));
      float sum = 0.f;
      for (int k = q; k < T_; k += 4) { float e = expf(Sc[row][k] - mx); Sc[row][k] = e; sum += e; }
      sum += __shfl_xor(sum, 1, 64);
      sum += __shfl_xor(sum, 2, 64);
      float inv = 1.f / sum;
      for (int k = q; k < T_; k += 4) Sc[row][k] *= inv;
    }
  }
  __syncthreads();
  for (int idx = tid; idx < T_ * 32; idx += 256) {
    int t = idx >> 5, d = idx & 31;
    float acc = 0.f;
    for (int k = 0; k < T_; ++k) acc += Sc[t][k] * V[k][d];
    attn_out[((size_t)(b * T_ + t)) * D_ + h * 32 + d] = f2bu(acc);
  }
}

// ---------------- capsule routing ----------------
__global__ __launch_bounds__(256) void cws_kernel(const float* __restrict__ x, const float* __restrict__ w_route,
                                                  const float* __restrict__ w_act, float* __restrict__ c_ws_out,
                                                  float* __restrict__ a_words) {
  int bl = blockIdx.x;
  int b = bl >> 6, l = bl & 63;
  __shared__ float word[256];
  __shared__ float logits[16];
  __shared__ float sred[4];
  int t = threadIdx.x;
  word[t] = x[((size_t)(b * T_ + l)) * D_ + t];
  __syncthreads();
  float pa = word[t] * w_act[t];
  float asum = block_reduce_sum_256(pa, sred);
  if (t == 0) a_words[b * 64 + l] = 1.f / (1.f + expf(-asum));
  int s = t >> 4, j0 = t & 15;
  float p = 0.f;
  for (int j = j0; j < 256; j += 16) p += w_route[((size_t)(l * 16 + s)) * 256 + j] * word[j];
#pragma unroll
  for (int m = 8; m >= 1; m >>= 1) p += __shfl_xor(p, m, 64);
  if (j0 == 0) logits[s] = p;
  __syncthreads();
  if (t < 16) {
    float mx = -1e30f;
#pragma unroll
    for (int k = 0; k < 16; ++k) mx = fmaxf(mx, logits[k]);
    float sum = 0.f;
#pragma unroll
    for (int k = 0; k < 16; ++k) sum += expf(logits[k] - mx);
    c_ws_out[(size_t)bl * 16 + t] = expf(logits[t] - mx) / sum;
  }
}

__global__ __launch_bounds__(64) void slot_agg_kernel(const float* __restrict__ c_ws, const float* __restrict__ a_words,
                                                      float* __restrict__ a_num, float* __restrict__ a_slots,
                                                      float* __restrict__ asl_sum) {
  int b = blockIdx.x, lane = threadIdx.x;
  float aw = a_words[b * 64 + lane];
  float asum = wave_reduce_sum(aw);
  float inv = 1.f / asum;
  float ssum = 0.f;
  for (int s = 0; s < 16; ++s) {
    float p = c_ws[((size_t)(b * 64 + lane)) * 16 + s] * aw;
    float r = wave_reduce_sum(p);
    if (lane == 0) {
      a_num[b * 16 + s] = r;
      a_slots[b * 16 + s] = r * inv;
      ssum += r * inv;
    }
  }
  if (lane == 0) asl_sum[b] = ssum;
}

// block = (lg, s, ihalf). Handles l = lg, lg+32 for i in [ihalf*128, +128).
__global__ __launch_bounds__(256, 4) void pose_ws3_kernel(const unsigned short* __restrict__ xbf,
                                                          const float* __restrict__ P,
                                                          const float* __restrict__ c_ws,
                                                          const float* __restrict__ a_words,
                                                          float* __restrict__ partial) {
  int bid = blockIdx.x;
  int ih = bid & 1, s = (bid >> 1) & 15, lg = bid >> 5;
  int iBase = ih * 128;
  __shared__ __align__(16) unsigned short Bs[32 * 256];  // 16KB weighted words [b][k]
  int tid = threadIdx.x, wid = tid >> 6, lane = tid & 63;
  int kg = lane >> 4, l15 = lane & 15;
  f32x4 acc[2][2];
#pragma unroll
  for (int i = 0; i < 2; ++i)
#pragma unroll
    for (int j = 0; j < 2; ++j) acc[i][j] = (f32x4){0.f, 0.f, 0.f, 0.f};

#pragma unroll
  for (int li = 0; li < 2; ++li) {
    int l = lg + li * 32;
    __syncthreads();
    {
      int b = tid >> 3, c0 = (tid & 7) * 4;
      float w = c_ws[((size_t)(b * 64 + l)) * 16 + s] * a_words[b * 64 + l];
      const unsigned short* src = xbf + ((size_t)(b * T_ + l)) * D_;
#pragma unroll
      for (int j = 0; j < 4; ++j) {
        int c = c0 + j;
        union { float4 f4; unsigned short u[8]; } in, out;
        in.f4 = *(const float4*)(src + c * 8);
#pragma unroll
        for (int e = 0; e < 8; ++e) out.u[e] = f2bu(w * b2f(in.u[e]));
        *(float4*)&Bs[b * 256 + ((c ^ (b & 7)) << 3)] = out.f4;
      }
    }
    __syncthreads();
    const float* Pbase = P + (((size_t)(l * 16 + s)) << 16);
#pragma unroll
    for (int k0 = 0; k0 < 256; k0 += 64) {
#pragma unroll
      for (int kk = 0; kk < 2; ++kk) {
        int cc = (k0 >> 3) + kk * 4 + kg;
        bf16x8 bfr[2];
#pragma unroll
        for (int fn = 0; fn < 2; ++fn) {
          int rb = fn * 16 + l15;
          bfr[fn] = *(const bf16x8*)&Bs[rb * 256 + ((cc ^ (rb & 7)) << 3)];
        }
        int kbase = k0 + kk * 32 + kg * 8;
#pragma unroll
        for (int fm = 0; fm < 2; ++fm) {
          int row = iBase + wid * 32 + fm * 16 + l15;
          const float* src = Pbase + (size_t)row * 256 + kbase;
          float4 v0 = *(const float4*)src;
          float4 v1 = *(const float4*)(src + 4);
          union { bf16x8 b8; unsigned short u[8]; } pk;
          pk.u[0] = f2bu(v0.x); pk.u[1] = f2bu(v0.y); pk.u[2] = f2bu(v0.z); pk.u[3] = f2bu(v0.w);
          pk.u[4] = f2bu(v1.x); pk.u[5] = f2bu(v1.y); pk.u[6] = f2bu(v1.z); pk.u[7] = f2bu(v1.w);
          acc[fm][0] = __builtin_amdgcn_mfma_f32_16x16x32_bf16(pk.b8, bfr[0], acc[fm][0], 0, 0, 0);
          acc[fm][1] = __builtin_amdgcn_mfma_f32_16x16x32_bf16(pk.b8, bfr[1], acc[fm][1], 0, 0, 0);
        }
      }
    }
  }
  float* pout = partial + ((size_t)(lg * 16 + s)) * 8192;
#pragma unroll
  for (int fm = 0; fm < 2; ++fm) {
#pragma unroll
    for (int fn = 0; fn < 2; ++fn) {
      int b = fn * 16 + l15;
      int i0 = iBase + wid * 32 + fm * 16 + (kg << 2);
#pragma unroll
      for (int r = 0; r < 4; ++r)
        pout[(i0 + r) * 32 + b] = acc[fm][fn][r];
    }
  }
}

// u_slots[(b*16+s)*256+i] = (sum_lg partial[(lg*16+s)][i*32+b]) / a_num[b*16+s]
__global__ __launch_bounds__(256) void reduce_uslots_kernel(const float* __restrict__ partial,
                                                            const float* __restrict__ a_num,
                                                            float* __restrict__ u_slots) {
  int s = blockIdx.x >> 5, ic = blockIdx.x & 31;
  int t = threadIdx.x;
  int i = ic * 8 + (t >> 5), b = t & 31;
  size_t off = (size_t)s * 8192 + i * 32 + b;
  float a0 = 0.f, a1 = 0.f, a2 = 0.f, a3 = 0.f;
#pragma unroll
  for (int lg = 0; lg < 32; lg += 4) {
    a0 += partial[((size_t)(lg + 0) * 16) * 8192 + off];
    a1 += partial[((size_t)(lg + 1) * 16) * 8192 + off];
    a2 += partial[((size_t)(lg + 2) * 16) * 8192 + off];
    a3 += partial[((size_t)(lg + 3) * 16) * 8192 + off];
  }
  u_slots[((size_t)(b * 16 + s)) * 256 + i] = (a0 + a1 + a2 + a3) / a_num[b * 16 + s];
}

__global__ __launch_bounds__(256) void csi_kernel(const float* __restrict__ u_slots, const float* __restrict__ w_route_si,
                                                  float* __restrict__ c_si) {
  int bs = blockIdx.x;
  int s = bs & 15;
  __shared__ float row[256];
  __shared__ float logits[16];
  int t = threadIdx.x;
  row[t] = u_slots[(size_t)bs * 256 + t];
  __syncthreads();
  int i = t >> 4, j0 = t & 15;
  float p = 0.f;
  for (int j = j0; j < 256; j += 16) p += w_route_si[((size_t)(s * 16 + i)) * 256 + j] * row[j];
#pragma unroll
  for (int m = 8; m >= 1; m >>= 1) p += __shfl_xor(p, m, 64);
  if (j0 == 0) logits[i] = p;
  __syncthreads();
  if (t < 16) {
    float mx = -1e30f;
#pragma unroll
    for (int k = 0; k < 16; ++k) mx = fmaxf(mx, logits[k]);
    float sum = 0.f;
#pragma unroll
    for (int k = 0; k < 16; ++k) sum += expf(logits[k] - mx);
    c_si[(size_t)bs * 16 + t] = expf(logits[t] - mx) / sum;
  }
}

// merged: an + argmax + u_pose for the argmax'd intent (reads R4 partials directly)
__global__ __launch_bounds__(256) void un_merged_kernel(const float* __restrict__ c_si,
                                                        const float* __restrict__ a_slots,
                                                        const float* __restrict__ R4,
                                                        const float* __restrict__ u_slots,
                                                        float* __restrict__ u_pose) {
  int b = blockIdx.x, t = threadIdx.x;
  __shared__ float csi_s[256];  // [s][i]
  __shared__ float asl_s[16];
  __shared__ float an_s[16];
  __shared__ float w_s[16];
  __shared__ float an_star;
  __shared__ int istar_s;
  csi_s[t] = c_si[(size_t)b * 256 + t];
  if (t < 16) asl_s[t] = a_slots[b * 16 + t];
  __syncthreads();
  if (t < 16) {
    float acc = 0.f;
#pragma unroll
    for (int s = 0; s < 16; ++s) acc += csi_s[s * 16 + t] * asl_s[s];
    an_s[t] = acc;
  }
  __syncthreads();
  if (t == 0) {
    int best = 0;
    float bv = an_s[0];
    for (int k = 1; k < 16; ++k)
      if (an_s[k] > bv) { bv = an_s[k]; best = k; }
    istar_s = best;
    an_star = bv;
  }
  __syncthreads();
  int istar = istar_s;
  if (t < 16) w_s[t] = csi_s[t * 16 + istar] * asl_s[t];
  __syncthreads();
  float acc = 0.f;
#pragma unroll
  for (int s = 0; s < 16; ++s) {
    size_t ro = ((size_t)(s * 16 + istar)) * 256 + t;
    float r = R4[ro] + R4[65536 + ro] + R4[131072 + ro] + R4[196608 + ro];
    acc += w_s[s] * r * u_slots[((size_t)(b * 16 + s)) * 256 + t];
  }
  u_pose[(size_t)b * 256 + t] = acc / (an_star + 1e-8f);
}

__global__ __launch_bounds__(128) void final_kernel(const float* __restrict__ x, const float* __restrict__ u_pose,
                                                    const float* __restrict__ cls_w,
                                                    const float* __restrict__ cls_b, const float* __restrict__ g,
                                                    const float* __restrict__ bb, float* __restrict__ out) {
  int b = blockIdx.x, m = threadIdx.x;
  __shared__ float row[512];
  __shared__ float sred[2];
  for (int d = m; d < 256; d += 128) {
    row[d] = x[((size_t)(b * T_ + L_)) * D_ + d];
    row[256 + d] = u_pose[(size_t)b * 256 + d];
  }
  __syncthreads();
  float acc = cls_b[m];
  for (int j = 0; j < 512; ++j) acc += cls_w[(size_t)m * 512 + j] * row[j];
  float v = wave_reduce_sum(acc);
  if ((m & 63) == 0) sred[m >> 6] = v;
  __syncthreads();
  float mean = (sred[0] + sred[1]) * (1.f / 128.f);
  __syncthreads();
  float dv = acc - mean;
  float v2 = wave_reduce_sum(dv * dv);
  if ((m & 63) == 0) sred[m >> 6] = v2;
  __syncthreads();
  float var = (sred[0] + sred[1]) * (1.f / 128.f);
  out[(size_t)b * 128 + m] = dv * (1.f / sqrtf(var + 1e-5f)) * g[m] + bb[m];
}

extern "C" void kernel_launch(void* const* d_in, const int* in_sizes, int n_in,
                              void* d_out, int out_size, void* d_ws, size_t ws_size,
                              hipStream_t stream) {
  (void)in_sizes; (void)n_in; (void)out_size; (void)ws_size;
  const float* dense      = (const float*)d_in[0];
  const float* sparse     = (const float*)d_in[1];
  const float* W_feat     = (const float*)d_in[2];
  const float* b_feat     = (const float*)d_in[3];
  const float* in_proj_w  = (const float*)d_in[4];
  const float* in_proj_b  = (const float*)d_in[5];
  const float* out_w      = (const float*)d_in[6];
  const float* out_b      = (const float*)d_in[7];
  const float* ln1_g      = (const float*)d_in[8];
  const float* ln1_b      = (const float*)d_in[9];
  const float* ln2_g      = (const float*)d_in[10];
  const float* ln2_b      = (const float*)d_in[11];
  const float* ff1_w      = (const float*)d_in[12];
  const float* ff1_b      = (const float*)d_in[13];
  const float* ff2_w      = (const float*)d_in[14];
  const float* ff2_b      = (const float*)d_in[15];
  const float* w_act      = (const float*)d_in[16];
  const float* w_route_ws = (const float*)d_in[17];
  const float* w_pose_ws  = (const float*)d_in[18];
  const float* w_route_si = (const float*)d_in[19];
  const float* w_pose_si  = (const float*)d_in[20];
  const float* cls_w      = (const float*)d_in[21];
  const float* cls_b      = (const float*)d_in[22];
  const float* inorm_g    = (const float*)d_in[23];
  const float* inorm_b    = (const float*)d_in[24];

  float* ws = (float*)d_ws;
  float* X       = ws;                 // 532480
  float* PROJ    = X + 532480;         // 532480
  float* a_words = PROJ + 532480;      // 2048
  float* a_num   = a_words + 2048;     // 512
  float* a_slots = a_num + 512;        // 512
  float* asl_sum = a_slots + 512;      // 32
  float* u_slots = asl_sum + 32;       // 131072
  float* c_si    = u_slots + 131072;   // 8192
  float* u_pose  = c_si + 8192;        // 8192
  float* R4      = u_pose + 8192;      // 262144

  unsigned short* bfb   = (unsigned short*)(R4 + 262144);
  unsigned short* Xbf   = bfb;                   // 532480
  unsigned short* QKVbf = Xbf + 532480;          // 1597440
  unsigned short* HAR   = QKVbf + 1597440;       // 4259840 (H; also CATbf, ATTNbf)
  unsigned short* CATbf = HAR;                   // 524288
  unsigned short* ATTNbf= HAR + 2097152;         // 532480
  unsigned short* wfeatT= HAR + 4259840;         // 65536
  unsigned short* ipwB  = wfeatT + 65536;        // 393216
  unsigned short* owB   = ipwB + 393216;         // 131072
  unsigned short* f1wB  = owB + 131072;          // 1048576
  unsigned short* f2wB  = f1wB + 1048576;        // 1048576
  // pose partials (16.78MB) reuse the then-dead bf16 arena from QKVbf on
  float* partial = (float*)QKVbf;

  float* c_ws_out    = (float*)d_out;          // 32768
  float* intents_out = (float*)d_out + 32768;  // 4096

  // converters + pose_si partial (one launch; pose_si depends only on inputs)
  conv_fused_kernel<<<5648, 256, 0, stream>>>(dense, sparse, CATbf, W_feat, wfeatT,
                                              in_proj_w, out_w, ff1_w, ff2_w,
                                              ipwB, owB, f1wB, f2wB,
                                              w_pose_si, R4);

  // featurizer
  gemm_bf2_kernel<0, 0, 1><<<dim3(4, 64), 256, 0, stream>>>(CATbf, wfeatT, b_feat, PROJ, nullptr, 2048, 256, 256);
  build_x_kernel<<<32, 256, 0, stream>>>(PROJ, X, Xbf);

  for (int layer = 0; layer < 2; ++layer) {
    const unsigned short* ipw = ipwB + (size_t)layer * 196608;
    const unsigned short* ow  = owB + (size_t)layer * 65536;
    const unsigned short* f1w = f1wB + (size_t)layer * 524288;
    const unsigned short* f2w = f2wB + (size_t)layer * 524288;
    const float* ipb = in_proj_b + (size_t)layer * 768;
    const float* ob  = out_b + (size_t)layer * 256;
    const float* g1  = ln1_g + (size_t)layer * 256;
    const float* b1  = ln1_b + (size_t)layer * 256;
    const float* g2  = ln2_g + (size_t)layer * 256;
    const float* b2  = ln2_b + (size_t)layer * 256;
    const float* f1b = ff1_b + (size_t)layer * DFF_;
    const float* f2b = ff2_b + (size_t)layer * 256;

    gemm_bf2_kernel<0, 1, 2><<<dim3(6, 65), 256, 0, stream>>>(Xbf, ipw, ipb, nullptr, QKVbf, NT_, 768, 256);
    attn_kernel<<<B_ * H_, 256, 0, stream>>>(QKVbf, ATTNbf);
    gemm_bf2_kernel<0, 0, 1><<<dim3(4, 65), 256, 0, stream>>>(ATTNbf, ow, ob, PROJ, nullptr, NT_, 256, 256);
    ln_residual_kernel<<<NT_, 256, 0, stream>>>(X, Xbf, PROJ, g1, b1);
    gemm_bf2_kernel<1, 1, 2><<<dim3(16, 65), 256, 0, stream>>>(Xbf, f1w, f1b, nullptr, HAR, NT_, DFF_, 256);
    gemm_bf2_kernel<0, 0, 1><<<dim3(4, 65), 256, 0, stream>>>(HAR, f2w, f2b, PROJ, nullptr, NT_, 256, 2048);
    ln_residual_kernel<<<NT_, 256, 0, stream>>>(X, Xbf, PROJ, g2, b2);
  }

  // capsule routing
  cws_kernel<<<2048, 256, 0, stream>>>(X, w_route_ws, w_act, c_ws_out, a_words);
  slot_agg_kernel<<<32, 64, 0, stream>>>(c_ws_out, a_words, a_num, a_slots, asl_sum);
  pose_ws3_kernel<<<1024, 256, 0, stream>>>(Xbf, w_pose_ws, c_ws_out, a_words, partial);
  reduce_uslots_kernel<<<512, 256, 0, stream>>>(partial, a_num, u_slots);
  csi_kernel<<<512, 256, 0, stream>>>(u_slots, w_route_si, c_si);
  un_merged_kernel<<<32, 256, 0, stream>>>(c_si, a_slots, R4, u_slots, u_pose);
  final_kernel<<<32, 128, 0, stream>>>(X, u_pose, cls_w, cls_b, inorm_g, inorm_b, intents_out);
}

// Round 12
// 275.588 us; speedup vs baseline: 1.1512x; 1.0184x over previous
//
#include <hip/hip_runtime.h>
#include <hip/hip_bf16.h>
#include <math.h>

// dims
#define B_ 32
#define L_ 64
#define D_ 256
#define H_ 8
#define T_ 65
#define NT_ (B_*T_)   // 2080
#define DFF_ 2048
#define S_ 16
#define I_ 16
#define DSEM_ 128

typedef __attribute__((ext_vector_type(8))) short bf16x8;
typedef __attribute__((ext_vector_type(4))) float f32x4;

typedef __attribute__((address_space(1))) const void gbl_void;
typedef __attribute__((address_space(3))) void lds_void;
#define GLOAD16(g, l) __builtin_amdgcn_global_load_lds((gbl_void*)(g), (lds_void*)(l), 16, 0, 0)

__device__ inline unsigned short f2bu(float f) {
  union { float f; unsigned u; } a; a.f = f;
  unsigned r = a.u + 0x7FFF + ((a.u >> 16) & 1);
  return (unsigned short)(r >> 16);
}
__device__ inline float b2f(unsigned short u) {
  union { unsigned u; float f; } a; a.u = ((unsigned)u) << 16;
  return a.f;
}

__device__ inline float wave_reduce_sum(float v) {
#pragma unroll
  for (int m = 32; m >= 1; m >>= 1) v += __shfl_xor(v, m, 64);
  return v;
}

__device__ inline float block_reduce_sum_256(float v, float* sred) {
  v = wave_reduce_sum(v);
  int tid = threadIdx.x;
  if ((tid & 63) == 0) sred[tid >> 6] = v;
  __syncthreads();
  float r = sred[0] + sred[1] + sred[2] + sred[3];
  __syncthreads();
  return r;
}

// ---------------- fused converters (concat | W_feat transpose | weight conv | pose_si partial) ----------------
__global__ __launch_bounds__(256) void conv_fused_kernel(
    const float* __restrict__ dense, const float* __restrict__ sparse, unsigned short* __restrict__ cat,
    const float* __restrict__ wfeat, unsigned short* __restrict__ wfeatT,
    const float* __restrict__ ipw, const float* __restrict__ ow,
    const float* __restrict__ f1w, const float* __restrict__ f2w,
    unsigned short* __restrict__ ipwB, unsigned short* __restrict__ owB,
    unsigned short* __restrict__ f1wB, unsigned short* __restrict__ f2wB,
    const float* __restrict__ Psi, float* __restrict__ R4) {
  __shared__ float tb[64][65];
  int bid = blockIdx.x, tid = threadIdx.x;
  if (bid < 2048) {
    int idx = bid * 256 + tid;
    int r = idx >> 8, c = idx & 255;
    float v = (c < 128) ? dense[r * 128 + c] : sparse[r * 128 + (c - 128)];
    cat[idx] = f2bu(v);
  } else if (bid < 2064) {
    int blk = bid - 2048;
    int k0 = (blk & 3) * 64, n0 = (blk >> 2) * 64;
    int wid = tid >> 6, lane = tid & 63;
#pragma unroll
    for (int p = 0; p < 16; ++p)
      tb[p * 4 + wid][lane] = wfeat[(size_t)(k0 + p * 4 + wid) * 256 + n0 + lane];
    __syncthreads();
#pragma unroll
    for (int p = 0; p < 16; ++p)
      wfeatT[(size_t)(n0 + p * 4 + wid) * 256 + k0 + lane] = f2bu(tb[lane][p * 4 + wid]);
  } else if (bid < 4624) {
    int i = (bid - 2064) * 256 + tid;  // over 655360 float4s
    const float* src; unsigned short* dst; int off;
    if (i < 98304)       { src = ipw; dst = ipwB; off = i; }
    else if (i < 131072) { src = ow;  dst = owB;  off = i - 98304; }
    else if (i < 393216) { src = f1w; dst = f1wB; off = i - 131072; }
    else                 { src = f2w; dst = f2wB; off = i - 393216; }
    float4 v = ((const float4*)src)[off];
    short4 o;
    o.x = (short)f2bu(v.x); o.y = (short)f2bu(v.y);
    o.z = (short)f2bu(v.z); o.w = (short)f2bu(v.w);
    ((short4*)dst)[off] = o;
  } else {
    // pose_si partial: R4[jc][si][k] = sum of 64 j's of w_pose_si[s,i,j,k]
    int idx = bid - 4624;              // 1024 blocks
    int si = idx >> 2, jc = idx & 3;
    int k = tid;
    const float* base = Psi + (size_t)si * 65536 + (size_t)jc * 64 * 256 + k;
    float a0 = 0.f, a1 = 0.f, a2 = 0.f, a3 = 0.f;
#pragma unroll
    for (int j = 0; j < 64; j += 4) {
      a0 += base[(j + 0) * 256];
      a1 += base[(j + 1) * 256];
      a2 += base[(j + 2) * 256];
      a3 += base[(j + 3) * 256];
    }
    R4[(size_t)jc * 65536 + si * 256 + k] = a0 + a1 + a2 + a3;
  }
}

// ---------------- bf16 MFMA GEMM (NT): C[M,N] = act(A[M,K] @ W[N,K]^T + bias) ----------------
template <int ACT, int OUT_BF16, int NFRAG>
__global__ __launch_bounds__(256) void gemm_bf2_kernel(const unsigned short* __restrict__ A,
                                                       const unsigned short* __restrict__ W,
                                                       const float* __restrict__ bias,
                                                       float* __restrict__ Cf, unsigned short* __restrict__ Cb,
                                                       int M, int N, int K) {
  __shared__ __align__(16) unsigned short As[2][32 * 64];
  __shared__ __align__(16) unsigned short Bs[2][NFRAG * 64 * 64];
  int tid = threadIdx.x, wid = tid >> 6, lane = tid & 63;
  int row0 = blockIdx.y * 32, col0 = blockIdx.x * (64 * NFRAG);
  int lr = lane >> 3;
  int sc = ((lane & 7) ^ (lr & 7)) << 3;
  const unsigned short* Asrc = A + (size_t)(row0 + wid * 8 + lr) * K + sc;
  const unsigned short* Bsrc[2 * NFRAG];
#pragma unroll
  for (int p = 0; p < 2 * NFRAG; ++p)
    Bsrc[p] = W + (size_t)(col0 + wid * 16 * NFRAG + p * 8 + lr) * K + sc;
  unsigned short* AsW = &As[0][0] + wid * (8 * 64);
  unsigned short* BsW = &Bs[0][0] + wid * (16 * NFRAG * 64);

  f32x4 acc[2][NFRAG];
#pragma unroll
  for (int i = 0; i < 2; ++i)
#pragma unroll
    for (int j = 0; j < NFRAG; ++j) acc[i][j] = (f32x4){0.f, 0.f, 0.f, 0.f};

  GLOAD16(Asrc, AsW);
#pragma unroll
  for (int p = 0; p < 2 * NFRAG; ++p) GLOAD16(Bsrc[p], BsW + p * (8 * 64));

  int nk = K >> 6, cur = 0;
  int kg = lane >> 4, l15 = lane & 15;
  for (int kt = 0; kt < nk; ++kt) {
    __syncthreads();
    if (kt + 1 < nk) {
      int k0 = (kt + 1) << 6;
      GLOAD16(Asrc + k0, AsW + (cur ^ 1) * (32 * 64));
#pragma unroll
      for (int p = 0; p < 2 * NFRAG; ++p)
        GLOAD16(Bsrc[p] + k0, BsW + (cur ^ 1) * (NFRAG * 64 * 64) + p * (8 * 64));
    }
    const unsigned short* Ab = &As[cur][0];
    const unsigned short* Bb = &Bs[cur][0];
#pragma unroll
    for (int kk = 0; kk < 2; ++kk) {
      int cc = kk * 4 + kg;
      bf16x8 bfr[NFRAG];
#pragma unroll
      for (int fn = 0; fn < NFRAG; ++fn) {
        int rn = wid * 16 * NFRAG + fn * 16 + l15;
        bfr[fn] = *(const bf16x8*)&Bb[rn * 64 + ((cc ^ (rn & 7)) << 3)];
      }
#pragma unroll
      for (int fm = 0; fm < 2; ++fm) {
        int rm = fm * 16 + l15;
        bf16x8 afr = *(const bf16x8*)&Ab[rm * 64 + ((cc ^ (rm & 7)) << 3)];
#pragma unroll
        for (int fn = 0; fn < NFRAG; ++fn)
          acc[fm][fn] = __builtin_amdgcn_mfma_f32_16x16x32_bf16(afr, bfr[fn], acc[fm][fn], 0, 0, 0);
      }
    }
    cur ^= 1;
  }
#pragma unroll
  for (int fm = 0; fm < 2; ++fm) {
#pragma unroll
    for (int fn = 0; fn < NFRAG; ++fn) {
      int col = col0 + wid * 16 * NFRAG + fn * 16 + l15;
      float bi = bias[col];
      int rbase = row0 + fm * 16 + ((lane >> 4) << 2);
#pragma unroll
      for (int r = 0; r < 4; ++r) {
        int grow = rbase + r;
        float v = acc[fm][fn][r] + bi;
        if (ACT == 1) v = fmaxf(v, 0.f);
        if (OUT_BF16) Cb[(size_t)grow * N + col] = f2bu(v);
        else          Cf[(size_t)grow * N + col] = v;
      }
    }
  }
}

// x = LN(x + proj) * g + b  (+ bf16 shadow)
__global__ __launch_bounds__(256) void ln_residual_kernel(float* __restrict__ x, unsigned short* __restrict__ xbf,
                                                          const float* __restrict__ proj,
                                                          const float* __restrict__ g, const float* __restrict__ bb) {
  __shared__ float sred[4];
  int r = blockIdx.x, d = threadIdx.x;
  float v = x[(size_t)r * D_ + d] + proj[(size_t)r * D_ + d];
  float mean = block_reduce_sum_256(v, sred) * (1.f / 256.f);
  float dv = v - mean;
  float var = block_reduce_sum_256(dv * dv, sred) * (1.f / 256.f);
  float o = dv * (1.f / sqrtf(var + 1e-5f)) * g[d] + bb[d];
  x[(size_t)r * D_ + d] = o;
  xbf[(size_t)r * D_ + d] = f2bu(o);
}

// x[b,l,:] = tok[b*64+l,:], x[b,64,:] = sum_l tok ; also bf16 shadow
__global__ void build_x_kernel(const float* __restrict__ tok, float* __restrict__ x,
                               unsigned short* __restrict__ xbf) {
  int b = blockIdx.x, d = threadIdx.x;
  float s = 0.f;
  for (int l = 0; l < L_; ++l) {
    float v = tok[((size_t)(b * L_ + l)) * D_ + d];
    size_t o = ((size_t)(b * T_ + l)) * D_ + d;
    x[o] = v; xbf[o] = f2bu(v);
    s += v;
  }
  size_t o = ((size_t)(b * T_ + L_)) * D_ + d;
  x[o] = s; xbf[o] = f2bu(s);
}

// ---------------- attention (2-way Q-row split; bf16 I/O, fp32 math) ----------------
__global__ __launch_bounds__(256) void attn_kernel(const unsigned short* __restrict__ qkv,
                                                   unsigned short* __restrict__ attn_out) {
  int bid = blockIdx.x;               // 512 blocks: (b,h,half)
  int half = bid & 1;
  int bh = bid >> 1;
  int b = bh >> 3, h = bh & 7;
  int t0 = half ? 33 : 0;
  int nrows = half ? 32 : 33;
  __shared__ float Q[33][32], K[T_][32], V[T_][32];
  __shared__ float Sc[33][T_ + 1];
  int tid = threadIdx.x;
  for (int idx = tid; idx < T_ * 32; idx += 256) {
    int t = idx >> 5, d = idx & 31;
    const unsigned short* base = qkv + ((size_t)(b * T_ + t)) * 768 + h * 32 + d;
    K[t][d] = b2f(base[256]);
    V[t][d] = b2f(base[512]);
    if (t >= t0 && t < t0 + nrows) Q[t - t0][d] = b2f(base[0]);
  }
  __syncthreads();
  for (int idx = tid; idx < nrows * T_; idx += 256) {
    int qi = idx / T_, ki = idx % T_;
    float s = 0.f;
#pragma unroll
    for (int d = 0; d < 32; ++d) s += Q[qi][d] * K[ki][d];
    Sc[qi][ki] = s * 0.17677669529663687f;
  }
  __syncthreads();
  {
    int q = tid & 3;
    for (int row = tid >> 2; row < nrows; row += 64) {
      float mx = -1e30f;
      for (int k = q; k < T_; k += 4) mx = fmaxf(mx, Sc[row][k]);
      mx = fmaxf(mx, __shfl_xor(mx, 1, 64));
      mx = fmaxf(mx, __shfl_xor(mx, 2, 64));
      float sum = 0.f;
      for (int k = q; k < T_; k += 4) { float e = expf(Sc[row][k] - mx); Sc[row][k] = e; sum += e; }
      sum += __shfl_xor(sum, 1, 64);
      sum += __shfl_xor(sum, 2, 64);
      float inv = 1.f / sum;
      for (int k = q; k < T_; k += 4) Sc[row][k] *= inv;
    }
  }
  __syncthreads();
  for (int idx = tid; idx < nrows * 32; idx += 256) {
    int t = idx >> 5, d = idx & 31;
    float acc = 0.f;
    for (int k = 0; k < T_; ++k) acc += Sc[t][k] * V[k][d];
    attn_out[((size_t)(b * T_ + t0 + t)) * D_ + h * 32 + d] = f2bu(acc);
  }
}

// ---------------- capsule routing ----------------
__global__ __launch_bounds__(256) void cws_kernel(const float* __restrict__ x, const float* __restrict__ w_route,
                                                  const float* __restrict__ w_act, float* __restrict__ c_ws_out,
                                                  float* __restrict__ a_words) {
  int bl = blockIdx.x;
  int b = bl >> 6, l = bl & 63;
  __shared__ float word[256];
  __shared__ float logits[16];
  __shared__ float sred[4];
  int t = threadIdx.x;
  word[t] = x[((size_t)(b * T_ + l)) * D_ + t];
  __syncthreads();
  float pa = word[t] * w_act[t];
  float asum = block_reduce_sum_256(pa, sred);
  if (t == 0) a_words[b * 64 + l] = 1.f / (1.f + expf(-asum));
  int s = t >> 4, j0 = t & 15;
  float p = 0.f;
  for (int j = j0; j < 256; j += 16) p += w_route[((size_t)(l * 16 + s)) * 256 + j] * word[j];
#pragma unroll
  for (int m = 8; m >= 1; m >>= 1) p += __shfl_xor(p, m, 64);
  if (j0 == 0) logits[s] = p;
  __syncthreads();
  if (t < 16) {
    float mx = -1e30f;
#pragma unroll
    for (int k = 0; k < 16; ++k) mx = fmaxf(mx, logits[k]);
    float sum = 0.f;
#pragma unroll
    for (int k = 0; k < 16; ++k) sum += expf(logits[k] - mx);
    c_ws_out[(size_t)bl * 16 + t] = expf(logits[t] - mx) / sum;
  }
}

__global__ __launch_bounds__(64) void slot_agg_kernel(const float* __restrict__ c_ws, const float* __restrict__ a_words,
                                                      float* __restrict__ a_num, float* __restrict__ a_slots,
                                                      float* __restrict__ asl_sum) {
  int b = blockIdx.x, lane = threadIdx.x;
  float aw = a_words[b * 64 + lane];
  float asum = wave_reduce_sum(aw);
  float inv = 1.f / asum;
  float ssum = 0.f;
  for (int s = 0; s < 16; ++s) {
    float p = c_ws[((size_t)(b * 64 + lane)) * 16 + s] * aw;
    float r = wave_reduce_sum(p);
    if (lane == 0) {
      a_num[b * 16 + s] = r;
      a_slots[b * 16 + s] = r * inv;
      ssum += r * inv;
    }
  }
  if (lane == 0) asl_sum[b] = ssum;
}

// block = (lg, s, ihalf). Handles l = lg, lg+32 for i in [ihalf*128, +128).
__global__ __launch_bounds__(256, 4) void pose_ws3_kernel(const unsigned short* __restrict__ xbf,
                                                          const float* __restrict__ P,
                                                          const float* __restrict__ c_ws,
                                                          const float* __restrict__ a_words,
                                                          float* __restrict__ partial) {
  int bid = blockIdx.x;
  int ih = bid & 1, s = (bid >> 1) & 15, lg = bid >> 5;
  int iBase = ih * 128;
  __shared__ __align__(16) unsigned short Bs[32 * 256];  // 16KB weighted words [b][k]
  int tid = threadIdx.x, wid = tid >> 6, lane = tid & 63;
  int kg = lane >> 4, l15 = lane & 15;
  f32x4 acc[2][2];
#pragma unroll
  for (int i = 0; i < 2; ++i)
#pragma unroll
    for (int j = 0; j < 2; ++j) acc[i][j] = (f32x4){0.f, 0.f, 0.f, 0.f};

#pragma unroll
  for (int li = 0; li < 2; ++li) {
    int l = lg + li * 32;
    __syncthreads();
    {
      int b = tid >> 3, c0 = (tid & 7) * 4;
      float w = c_ws[((size_t)(b * 64 + l)) * 16 + s] * a_words[b * 64 + l];
      const unsigned short* src = xbf + ((size_t)(b * T_ + l)) * D_;
#pragma unroll
      for (int j = 0; j < 4; ++j) {
        int c = c0 + j;
        union { float4 f4; unsigned short u[8]; } in, out;
        in.f4 = *(const float4*)(src + c * 8);
#pragma unroll
        for (int e = 0; e < 8; ++e) out.u[e] = f2bu(w * b2f(in.u[e]));
        *(float4*)&Bs[b * 256 + ((c ^ (b & 7)) << 3)] = out.f4;
      }
    }
    __syncthreads();
    const float* Pbase = P + (((size_t)(l * 16 + s)) << 16);
#pragma unroll
    for (int k0 = 0; k0 < 256; k0 += 64) {
#pragma unroll
      for (int kk = 0; kk < 2; ++kk) {
        int cc = (k0 >> 3) + kk * 4 + kg;
        bf16x8 bfr[2];
#pragma unroll
        for (int fn = 0; fn < 2; ++fn) {
          int rb = fn * 16 + l15;
          bfr[fn] = *(const bf16x8*)&Bs[rb * 256 + ((cc ^ (rb & 7)) << 3)];
        }
        int kbase = k0 + kk * 32 + kg * 8;
#pragma unroll
        for (int fm = 0; fm < 2; ++fm) {
          int row = iBase + wid * 32 + fm * 16 + l15;
          const float* src = Pbase + (size_t)row * 256 + kbase;
          float4 v0 = *(const float4*)src;
          float4 v1 = *(const float4*)(src + 4);
          union { bf16x8 b8; unsigned short u[8]; } pk;
          pk.u[0] = f2bu(v0.x); pk.u[1] = f2bu(v0.y); pk.u[2] = f2bu(v0.z); pk.u[3] = f2bu(v0.w);
          pk.u[4] = f2bu(v1.x); pk.u[5] = f2bu(v1.y); pk.u[6] = f2bu(v1.z); pk.u[7] = f2bu(v1.w);
          acc[fm][0] = __builtin_amdgcn_mfma_f32_16x16x32_bf16(pk.b8, bfr[0], acc[fm][0], 0, 0, 0);
          acc[fm][1] = __builtin_amdgcn_mfma_f32_16x16x32_bf16(pk.b8, bfr[1], acc[fm][1], 0, 0, 0);
        }
      }
    }
  }
  float* pout = partial + ((size_t)(lg * 16 + s)) * 8192;
#pragma unroll
  for (int fm = 0; fm < 2; ++fm) {
#pragma unroll
    for (int fn = 0; fn < 2; ++fn) {
      int b = fn * 16 + l15;
      int i0 = iBase + wid * 32 + fm * 16 + (kg << 2);
#pragma unroll
      for (int r = 0; r < 4; ++r)
        pout[(i0 + r) * 32 + b] = acc[fm][fn][r];
    }
  }
}

// u_slots[(b*16+s)*256+i] = (sum_lg partial[(lg*16+s)][i*32+b]) / a_num[b*16+s]
__global__ __launch_bounds__(256) void reduce_uslots_kernel(const float* __restrict__ partial,
                                                            const float* __restrict__ a_num,
                                                            float* __restrict__ u_slots) {
  int s = blockIdx.x >> 5, ic = blockIdx.x & 31;
  int t = threadIdx.x;
  int i = ic * 8 + (t >> 5), b = t & 31;
  size_t off = (size_t)s * 8192 + i * 32 + b;
  float a0 = 0.f, a1 = 0.f, a2 = 0.f, a3 = 0.f;
#pragma unroll
  for (int lg = 0; lg < 32; lg += 4) {
    a0 += partial[((size_t)(lg + 0) * 16) * 8192 + off];
    a1 += partial[((size_t)(lg + 1) * 16) * 8192 + off];
    a2 += partial[((size_t)(lg + 2) * 16) * 8192 + off];
    a3 += partial[((size_t)(lg + 3) * 16) * 8192 + off];
  }
  u_slots[((size_t)(b * 16 + s)) * 256 + i] = (a0 + a1 + a2 + a3) / a_num[b * 16 + s];
}

__global__ __launch_bounds__(256) void csi_kernel(const float* __restrict__ u_slots, const float* __restrict__ w_route_si,
                                                  float* __restrict__ c_si) {
  int bs = blockIdx.x;
  int s = bs & 15;
  __shared__ float row[256];
  __shared__ float logits[16];
  int t = threadIdx.x;
  row[t] = u_slots[(size_t)bs * 256 + t];
  __syncthreads();
  int i = t >> 4, j0 = t & 15;
  float p = 0.f;
  for (int j = j0; j < 256; j += 16) p += w_route_si[((size_t)(s * 16 + i)) * 256 + j] * row[j];
#pragma unroll
  for (int m = 8; m >= 1; m >>= 1) p += __shfl_xor(p, m, 64);
  if (j0 == 0) logits[i] = p;
  __syncthreads();
  if (t < 16) {
    float mx = -1e30f;
#pragma unroll
    for (int k = 0; k < 16; ++k) mx = fmaxf(mx, logits[k]);
    float sum = 0.f;
#pragma unroll
    for (int k = 0; k < 16; ++k) sum += expf(logits[k] - mx);
    c_si[(size_t)bs * 16 + t] = expf(logits[t] - mx) / sum;
  }
}

// merged: an + argmax + u_pose for the argmax'd intent (reads R4 partials directly)
__global__ __launch_bounds__(256) void un_merged_kernel(const float* __restrict__ c_si,
                                                        const float* __restrict__ a_slots,
                                                        const float* __restrict__ R4,
                                                        const float* __restrict__ u_slots,
                                                        float* __restrict__ u_pose) {
  int b = blockIdx.x, t = threadIdx.x;
  __shared__ float csi_s[256];  // [s][i]
  __shared__ float asl_s[16];
  __shared__ float an_s[16];
  __shared__ float w_s[16];
  __shared__ float an_star;
  __shared__ int istar_s;
  csi_s[t] = c_si[(size_t)b * 256 + t];
  if (t < 16) asl_s[t] = a_slots[b * 16 + t];
  __syncthreads();
  if (t < 16) {
    float acc = 0.f;
#pragma unroll
    for (int s = 0; s < 16; ++s) acc += csi_s[s * 16 + t] * asl_s[s];
    an_s[t] = acc;
  }
  __syncthreads();
  if (t == 0) {
    int best = 0;
    float bv = an_s[0];
    for (int k = 1; k < 16; ++k)
      if (an_s[k] > bv) { bv = an_s[k]; best = k; }
    istar_s = best;
    an_star = bv;
  }
  __syncthreads();
  int istar = istar_s;
  if (t < 16) w_s[t] = csi_s[t * 16 + istar] * asl_s[t];
  __syncthreads();
  float acc = 0.f;
#pragma unroll
  for (int s = 0; s < 16; ++s) {
    size_t ro = ((size_t)(s * 16 + istar)) * 256 + t;
    float r = R4[ro] + R4[65536 + ro] + R4[131072 + ro] + R4[196608 + ro];
    acc += w_s[s] * r * u_slots[((size_t)(b * 16 + s)) * 256 + t];
  }
  u_pose[(size_t)b * 256 + t] = acc / (an_star + 1e-8f);
}

__global__ __launch_bounds__(128) void final_kernel(const float* __restrict__ x, const float* __restrict__ u_pose,
                                                    const float* __restrict__ cls_w,
                                                    const float* __restrict__ cls_b, const float* __restrict__ g,
                                                    const float* __restrict__ bb, float* __restrict__ out) {
  int b = blockIdx.x, m = threadIdx.x;
  __shared__ float row[512];
  __shared__ float sred[2];
  for (int d = m; d < 256; d += 128) {
    row[d] = x[((size_t)(b * T_ + L_)) * D_ + d];
    row[256 + d] = u_pose[(size_t)b * 256 + d];
  }
  __syncthreads();
  float acc = cls_b[m];
  for (int j = 0; j < 512; ++j) acc += cls_w[(size_t)m * 512 + j] * row[j];
  float v = wave_reduce_sum(acc);
  if ((m & 63) == 0) sred[m >> 6] = v;
  __syncthreads();
  float mean = (sred[0] + sred[1]) * (1.f / 128.f);
  __syncthreads();
  float dv = acc - mean;
  float v2 = wave_reduce_sum(dv * dv);
  if ((m & 63) == 0) sred[m >> 6] = v2;
  __syncthreads();
  float var = (sred[0] + sred[1]) * (1.f / 128.f);
  out[(size_t)b * 128 + m] = dv * (1.f / sqrtf(var + 1e-5f)) * g[m] + bb[m];
}

extern "C" void kernel_launch(void* const* d_in, const int* in_sizes, int n_in,
                              void* d_out, int out_size, void* d_ws, size_t ws_size,
                              hipStream_t stream) {
  (void)in_sizes; (void)n_in; (void)out_size; (void)ws_size;
  const float* dense      = (const float*)d_in[0];
  const float* sparse     = (const float*)d_in[1];
  const float* W_feat     = (const float*)d_in[2];
  const float* b_feat     = (const float*)d_in[3];
  const float* in_proj_w  = (const float*)d_in[4];
  const float* in_proj_b  = (const float*)d_in[5];
  const float* out_w      = (const float*)d_in[6];
  const float* out_b      = (const float*)d_in[7];
  const float* ln1_g      = (const float*)d_in[8];
  const float* ln1_b      = (const float*)d_in[9];
  const float* ln2_g      = (const float*)d_in[10];
  const float* ln2_b      = (const float*)d_in[11];
  const float* ff1_w      = (const float*)d_in[12];
  const float* ff1_b      = (const float*)d_in[13];
  const float* ff2_w      = (const float*)d_in[14];
  const float* ff2_b      = (const float*)d_in[15];
  const float* w_act      = (const float*)d_in[16];
  const float* w_route_ws = (const float*)d_in[17];
  const float* w_pose_ws  = (const float*)d_in[18];
  const float* w_route_si = (const float*)d_in[19];
  const float* w_pose_si  = (const float*)d_in[20];
  const float* cls_w      = (const float*)d_in[21];
  const float* cls_b      = (const float*)d_in[22];
  const float* inorm_g    = (const float*)d_in[23];
  const float* inorm_b    = (const float*)d_in[24];

  float* ws = (float*)d_ws;
  float* X       = ws;                 // 532480
  float* PROJ    = X + 532480;         // 532480
  float* a_words = PROJ + 532480;      // 2048
  float* a_num   = a_words + 2048;     // 512
  float* a_slots = a_num + 512;        // 512
  float* asl_sum = a_slots + 512;      // 32
  float* u_slots = asl_sum + 32;       // 131072
  float* c_si    = u_slots + 131072;   // 8192
  float* u_pose  = c_si + 8192;        // 8192
  float* R4      = u_pose + 8192;      // 262144

  unsigned short* bfb   = (unsigned short*)(R4 + 262144);
  unsigned short* Xbf   = bfb;                   // 532480
  unsigned short* QKVbf = Xbf + 532480;          // 1597440
  unsigned short* HAR   = QKVbf + 1597440;       // 4259840 (H; also CATbf, ATTNbf)
  unsigned short* CATbf = HAR;                   // 524288
  unsigned short* ATTNbf= HAR + 2097152;         // 532480
  unsigned short* wfeatT= HAR + 4259840;         // 65536
  unsigned short* ipwB  = wfeatT + 65536;        // 393216
  unsigned short* owB   = ipwB + 393216;         // 131072
  unsigned short* f1wB  = owB + 131072;          // 1048576
  unsigned short* f2wB  = f1wB + 1048576;        // 1048576
  // pose partials (16.78MB) reuse the then-dead bf16 arena from QKVbf on
  float* partial = (float*)QKVbf;

  float* c_ws_out    = (float*)d_out;          // 32768
  float* intents_out = (float*)d_out + 32768;  // 4096

  // converters + pose_si partial (one launch; pose_si depends only on inputs)
  conv_fused_kernel<<<5648, 256, 0, stream>>>(dense, sparse, CATbf, W_feat, wfeatT,
                                              in_proj_w, out_w, ff1_w, ff2_w,
                                              ipwB, owB, f1wB, f2wB,
                                              w_pose_si, R4);

  // featurizer
  gemm_bf2_kernel<0, 0, 1><<<dim3(4, 64), 256, 0, stream>>>(CATbf, wfeatT, b_feat, PROJ, nullptr, 2048, 256, 256);
  build_x_kernel<<<32, 256, 0, stream>>>(PROJ, X, Xbf);

  for (int layer = 0; layer < 2; ++layer) {
    const unsigned short* ipw = ipwB + (size_t)layer * 196608;
    const unsigned short* ow  = owB + (size_t)layer * 65536;
    const unsigned short* f1w = f1wB + (size_t)layer * 524288;
    const unsigned short* f2w = f2wB + (size_t)layer * 524288;
    const float* ipb = in_proj_b + (size_t)layer * 768;
    const float* ob  = out_b + (size_t)layer * 256;
    const float* g1  = ln1_g + (size_t)layer * 256;
    const float* b1  = ln1_b + (size_t)layer * 256;
    const float* g2  = ln2_g + (size_t)layer * 256;
    const float* b2  = ln2_b + (size_t)layer * 256;
    const float* f1b = ff1_b + (size_t)layer * DFF_;
    const float* f2b = ff2_b + (size_t)layer * 256;

    gemm_bf2_kernel<0, 1, 2><<<dim3(6, 65), 256, 0, stream>>>(Xbf, ipw, ipb, nullptr, QKVbf, NT_, 768, 256);
    attn_kernel<<<B_ * H_ * 2, 256, 0, stream>>>(QKVbf, ATTNbf);
    gemm_bf2_kernel<0, 0, 1><<<dim3(4, 65), 256, 0, stream>>>(ATTNbf, ow, ob, PROJ, nullptr, NT_, 256, 256);
    ln_residual_kernel<<<NT_, 256, 0, stream>>>(X, Xbf, PROJ, g1, b1);
    gemm_bf2_kernel<1, 1, 2><<<dim3(16, 65), 256, 0, stream>>>(Xbf, f1w, f1b, nullptr, HAR, NT_, DFF_, 256);
    gemm_bf2_kernel<0, 0, 1><<<dim3(4, 65), 256, 0, stream>>>(HAR, f2w, f2b, PROJ, nullptr, NT_, 256, 2048);
    ln_residual_kernel<<<NT_, 256, 0, stream>>>(X, Xbf, PROJ, g2, b2);
  }

  // capsule routing
  cws_kernel<<<2048, 256, 0, stream>>>(X, w_route_ws, w_act, c_ws_out, a_words);
  slot_agg_kernel<<<32, 64, 0, stream>>>(c_ws_out, a_words, a_num, a_slots, asl_sum);
  pose_ws3_kernel<<<1024, 256, 0, stream>>>(Xbf, w_pose_ws, c_ws_out, a_words, partial);
  reduce_uslots_kernel<<<512, 256, 0, stream>>>(partial, a_num, u_slots);
  csi_kernel<<<512, 256, 0, stream>>>(u_slots, w_route_si, c_si);
  un_merged_kernel<<<32, 256, 0, stream>>>(c_si, a_slots, R4, u_slots, u_pose);
  final_kernel<<<32, 128, 0, stream>>>(X, u_pose, cls_w, cls_b, inorm_g, inorm_b, intents_out);
}